// Round 2
// baseline (7466.792 us; speedup 1.0000x reference)
//
#include <hip/hip_runtime.h>

#define B 2048
#define NF 39
#define D 16
#define CIN_O 200
#define HHALF 100

// ---------------------------------------------------------------------------
// K1: embedding gather + scale, and bias-embedding row-sum
// inputs[b][f][d] = emb[id[b][f]][d] * val[b][f]   (B,39,16)
// biassum[b]      = sum_f bias_emb[id[b][f]] * val[b][f]
// ---------------------------------------------------------------------------
__global__ __launch_bounds__(256) void gather_kernel(
    const int* __restrict__ fid, const float* __restrict__ fval,
    const float* __restrict__ emb, const float* __restrict__ bias_emb,
    float* __restrict__ inputs, float* __restrict__ biassum) {
  int b = blockIdx.x;
  __shared__ int ids[NF];
  __shared__ float vals[NF];
  int t = threadIdx.x;
  if (t < NF) { ids[t] = fid[b * NF + t]; vals[t] = fval[b * NF + t]; }
  __syncthreads();
  for (int i = t; i < NF * D; i += 256) {
    int f = i >> 4, d = i & 15;
    inputs[b * NF * D + i] = emb[(long)ids[f] * D + d] * vals[f];
  }
  if (t < 64) {
    float pb = (t < NF) ? bias_emb[ids[t]] * vals[t] : 0.f;
#pragma unroll
    for (int m = 32; m >= 1; m >>= 1) pb += __shfl_xor(pb, m);
    if (t == 0) biassum[b] = pb;
  }
}

// ---------------------------------------------------------------------------
// K2: pad CIN weight rows from 39 to 40 floats (16B-aligned float4 rows)
// Wp[o][h][m] = (m<39) ? W[o][h*39+m] : 0
// ---------------------------------------------------------------------------
__global__ void pad_w_kernel(const float* __restrict__ W, float* __restrict__ Wp,
                             int total) {
  int idx = blockIdx.x * blockDim.x + threadIdx.x;
  if (idx >= total) return;
  int m = idx % 40;
  int rest = idx / 40;  // = o*H + h
  Wp[idx] = (m < 39) ? W[rest * 39 + m] : 0.f;
}

// ---------------------------------------------------------------------------
// K3: one CIN layer.
// out[b,o,d] = relu( sum_{h,m} Wp[o,h,m] * Hin[b,h,d] * Z[b,m,d] + bias[o] )
// SPLIT=1: o<100 -> h_next ; o>=100 -> cin_out col (off + o-100), d-summed
// SPLIT=0: all o -> cin_out col (off + o), d-summed
// Block = one b, 256 threads: d = tid&15, og = tid>>4, o = og + 16k.
// Z column kept in registers (no LDS operand in the inner dot).
// ---------------------------------------------------------------------------
template <int H, int SPLIT>
__global__ __launch_bounds__(256) void cin_kernel(
    const float* __restrict__ Zin, const float* __restrict__ Hin,
    const float* __restrict__ Wp, const float* __restrict__ bias,
    float* __restrict__ h_next, float* __restrict__ cin_out, int col_offset) {
  int b = blockIdx.x;
  int t = threadIdx.x;
  int d = t & 15, og = t >> 4;
  __shared__ float Hs[H * D];
  for (int i = t; i < H * D; i += 256) Hs[i] = Hin[b * H * D + i];
  __syncthreads();

  float z[40];
#pragma unroll
  for (int m = 0; m < 39; ++m) z[m] = Zin[b * NF * D + m * D + d];
  z[39] = 0.f;

  for (int o = og; o < CIN_O; o += 16) {
    float acc = bias[o];
    const float4* w = reinterpret_cast<const float4*>(Wp + (long)o * H * 40);
#pragma unroll 2
    for (int h = 0; h < H; ++h) {
      const float4* wr = w + h * 10;
      float a = Hs[h * D + d];
      float g0 = 0.f, g1 = 0.f;
#pragma unroll
      for (int m4 = 0; m4 < 10; ++m4) {
        float4 wv = wr[m4];
        float s = wv.x * z[4 * m4 + 0] + wv.y * z[4 * m4 + 1] +
                  wv.z * z[4 * m4 + 2] + wv.w * z[4 * m4 + 3];
        if (m4 & 1) g1 += s; else g0 += s;
      }
      acc += a * (g0 + g1);
    }
    float x = fmaxf(acc, 0.f);
    if (SPLIT && o < HHALF) {
      h_next[b * HHALF * D + o * D + d] = x;
    } else {
      float s = x;
      s += __shfl_xor(s, 1);
      s += __shfl_xor(s, 2);
      s += __shfl_xor(s, 4);
      s += __shfl_xor(s, 8);
      if (d == 0) {
        int col = col_offset + (SPLIT ? o - HHALF : o);
        cin_out[b * 400 + col] = s;
      }
    }
  }
}

// ---------------------------------------------------------------------------
// K4: DNN layer  out[b,o] = relu( x[b,:] . W[o,:] + bias[o] ), 4 batches/block
// ---------------------------------------------------------------------------
template <int IN>
__global__ __launch_bounds__(256) void dnn_kernel(
    const float* __restrict__ x, const float* __restrict__ W,
    const float* __restrict__ bias, float* __restrict__ out) {
  int b0 = blockIdx.x * 4;
  int t = threadIdx.x;
  __shared__ __align__(16) float xs[4 * IN];
  for (int i = t; i < 4 * IN; i += 256) xs[i] = x[(long)b0 * IN + i];
  __syncthreads();
  const float4* xs4 = reinterpret_cast<const float4*>(xs);
  for (int o = t; o < 400; o += 256) {
    const float4* w = reinterpret_cast<const float4*>(W + (long)o * IN);
    float a0 = bias[o], a1 = a0, a2 = a0, a3 = a0;
    for (int k = 0; k < IN / 4; ++k) {
      float4 wv = w[k];
      float4 x0 = xs4[0 * (IN / 4) + k];
      float4 x1 = xs4[1 * (IN / 4) + k];
      float4 x2 = xs4[2 * (IN / 4) + k];
      float4 x3 = xs4[3 * (IN / 4) + k];
      a0 += wv.x * x0.x + wv.y * x0.y + wv.z * x0.z + wv.w * x0.w;
      a1 += wv.x * x1.x + wv.y * x1.y + wv.z * x1.z + wv.w * x1.w;
      a2 += wv.x * x2.x + wv.y * x2.y + wv.z * x2.z + wv.w * x2.w;
      a3 += wv.x * x3.x + wv.y * x3.y + wv.z * x3.z + wv.w * x3.w;
    }
    out[(long)(b0 + 0) * 400 + o] = fmaxf(a0, 0.f);
    out[(long)(b0 + 1) * 400 + o] = fmaxf(a1, 0.f);
    out[(long)(b0 + 2) * 400 + o] = fmaxf(a2, 0.f);
    out[(long)(b0 + 3) * 400 + o] = fmaxf(a3, 0.f);
  }
}

// ---------------------------------------------------------------------------
// K5: final FC: out[b] = concat(cin(400), dnn(400)) . fcW + fcb + biassum[b]
// ---------------------------------------------------------------------------
__global__ __launch_bounds__(256) void final_kernel(
    const float* __restrict__ cin, const float* __restrict__ d1,
    const float* __restrict__ fcW, const float* __restrict__ fcb,
    const float* __restrict__ biassum, float* __restrict__ out) {
  int b = blockIdx.x, t = threadIdx.x;
  float p = 0.f;
  for (int i = t; i < 800; i += 256) {
    float v = (i < 400) ? cin[b * 400 + i] : d1[b * 400 + (i - 400)];
    p += v * fcW[i];
  }
#pragma unroll
  for (int m = 32; m >= 1; m >>= 1) p += __shfl_xor(p, m);
  __shared__ float red[4];
  if ((t & 63) == 0) red[t >> 6] = p;
  __syncthreads();
  if (t == 0) out[b] = red[0] + red[1] + red[2] + red[3] + fcb[0] + biassum[b];
}

// ---------------------------------------------------------------------------
extern "C" void kernel_launch(void* const* d_in, const int* in_sizes, int n_in,
                              void* d_out, int out_size, void* d_ws,
                              size_t ws_size, hipStream_t stream) {
  (void)in_sizes; (void)n_in; (void)out_size; (void)ws_size;
  const int* fid = (const int*)d_in[0];
  const float* fval = (const float*)d_in[1];
  const float* emb = (const float*)d_in[2];
  const float* bias_emb = (const float*)d_in[3];
  const float* cW0 = (const float*)d_in[4];
  const float* cb0 = (const float*)d_in[5];
  const float* cW1 = (const float*)d_in[6];
  const float* cb1 = (const float*)d_in[7];
  const float* cW2 = (const float*)d_in[8];
  const float* cb2 = (const float*)d_in[9];
  const float* dW0 = (const float*)d_in[10];
  const float* db0 = (const float*)d_in[11];
  const float* dW1 = (const float*)d_in[12];
  const float* db1 = (const float*)d_in[13];
  const float* fcW = (const float*)d_in[14];
  const float* fcb = (const float*)d_in[15];
  float* out = (float*)d_out;

  float* ws = (float*)d_ws;
  float* inputs = ws;  ws += B * NF * D;        // 1,277,952
  float* biassum = ws; ws += B;                 // 2,048
  float* h1 = ws;      ws += B * HHALF * D;     // 3,276,800
  float* h2 = ws;      ws += B * HHALF * D;     // 3,276,800
  float* cinres = ws;  ws += B * 400;           // 819,200
  float* dd0 = ws;     ws += B * 400;           // 819,200
  float* dd1 = ws;     ws += B * 400;           // 819,200
  float* Wp0 = ws;     ws += 200 * 39 * 40;     // 312,000
  float* Wp1 = ws;     ws += 200 * 100 * 40;    // 800,000
  float* Wp2 = ws;     ws += 200 * 100 * 40;    // 800,000
  // total ~44.8 MB of workspace

  gather_kernel<<<B, 256, 0, stream>>>(fid, fval, emb, bias_emb, inputs, biassum);

  int tot0 = 200 * 39 * 40, tot12 = 200 * 100 * 40;
  pad_w_kernel<<<(tot0 + 255) / 256, 256, 0, stream>>>(cW0, Wp0, tot0);
  pad_w_kernel<<<(tot12 + 255) / 256, 256, 0, stream>>>(cW1, Wp1, tot12);
  pad_w_kernel<<<(tot12 + 255) / 256, 256, 0, stream>>>(cW2, Wp2, tot12);

  cin_kernel<39, 1><<<B, 256, 0, stream>>>(inputs, inputs, Wp0, cb0, h1, cinres, 0);
  cin_kernel<100, 1><<<B, 256, 0, stream>>>(inputs, h1, Wp1, cb1, h2, cinres, 100);
  cin_kernel<100, 0><<<B, 256, 0, stream>>>(inputs, h2, Wp2, cb2, nullptr, cinres, 200);

  dnn_kernel<624><<<B / 4, 256, 0, stream>>>(inputs, dW0, db0, dd0);
  dnn_kernel<400><<<B / 4, 256, 0, stream>>>(dd0, dW1, db1, dd1);

  final_kernel<<<B, 256, 0, stream>>>(cinres, dd1, fcW, fcb, biassum, out);
}

// Round 3
// 508.761 us; speedup vs baseline: 14.6764x; 14.6764x over previous
//
#include <hip/hip_runtime.h>

#define B 2048
#define NF 39
#define D 16
#define CIN_O 200
#define HHALF 100

typedef __bf16 bf16x8 __attribute__((ext_vector_type(8)));
typedef float f32x4 __attribute__((ext_vector_type(4)));

// ---------------------------------------------------------------------------
// K1: embedding gather + scale, and bias-embedding row-sum
// ---------------------------------------------------------------------------
__global__ __launch_bounds__(256) void gather_kernel(
    const int* __restrict__ fid, const float* __restrict__ fval,
    const float* __restrict__ emb, const float* __restrict__ bias_emb,
    float* __restrict__ inputs, float* __restrict__ biassum) {
  int b = blockIdx.x;
  __shared__ int ids[NF];
  __shared__ float vals[NF];
  int t = threadIdx.x;
  if (t < NF) { ids[t] = fid[b * NF + t]; vals[t] = fval[b * NF + t]; }
  __syncthreads();
  for (int i = t; i < NF * D; i += 256) {
    int f = i >> 4, d = i & 15;
    inputs[b * NF * D + i] = emb[(long)ids[f] * D + d] * vals[f];
  }
  if (t < 64) {
    float pb = (t < NF) ? bias_emb[ids[t]] * vals[t] : 0.f;
#pragma unroll
    for (int m = 32; m >= 1; m >>= 1) pb += __shfl_xor(pb, m);
    if (t == 0) biassum[b] = pb;
  }
}

// ---------------------------------------------------------------------------
// K2: pack CIN weights into bf16 MFMA A-fragment layout.
// k' = h*40 + m  (m padded 39->40; layer0 h padded 39->40).
// Wg[((c*13 + mt)*64 + l)*8 + j] = W[o = mt*16 + (l&15)][k = c*32+(l>>4)*8+j]
// ---------------------------------------------------------------------------
__global__ void prep_w_kernel(const float* __restrict__ W, __bf16* __restrict__ Wg,
                              int Hreal, int nch) {
  int idx = blockIdx.x * 256 + threadIdx.x;  // one thread per (c, mt, l)
  int total = nch * 13 * 64;
  if (idx >= total) return;
  int l = idx & 63;
  int mt = (idx >> 6) % 13;
  int c = idx / (13 * 64);
  int o = mt * 16 + (l & 15);
  int kb = c * 32 + ((l >> 4) << 3);
  int rowlen = Hreal * 39;
  bf16x8 v;
#pragma unroll
  for (int j = 0; j < 8; ++j) {
    int k = kb + j;
    int h = k / 40;
    int m = k - h * 40;
    float val = 0.f;
    if (o < 200 && h < Hreal && m < 39) val = W[(long)o * rowlen + h * 39 + m];
    v[j] = (__bf16)val;
  }
  *reinterpret_cast<bf16x8*>(Wg + (long)idx * 8) = v;
}

// ---------------------------------------------------------------------------
// K3: CIN layer as fused outer-product GEMM with bf16 MFMA (16x16x32).
// out[o, n=(b,d)] = relu( sum_k W[o,k] * H[b,h(k),d]*Z[b,m(k),d] + bias[o] )
// Block: 4 b's (64 cols), 256 thr = 4 waves = 2 M-halves x 2 col-groups.
// Wave: 7 M-tiles (halves overlap on tile 6 -> idempotent dup stores) x 32 cols.
// Per K-chunk(32): 7 global W-frag loads, 2 B-frag forms (LDS H,Z), 14 MFMA.
// No barriers in the K-loop.
// ---------------------------------------------------------------------------
template <int HH, int SPLIT>
__global__ __launch_bounds__(256, 2) void cin_mfma_kernel(
    const float* __restrict__ Zin, const float* __restrict__ Hin,
    const __bf16* __restrict__ Wg, const float* __restrict__ bias,
    float* __restrict__ h_next, float* __restrict__ cin_out, int col_offset) {
  constexpr int HR = (HH == 40) ? 39 : 100;  // real h rows in Hin
  constexpr int NCH = HH * 40 / 32;          // K-chunks
  __shared__ float Hs[4 * HH * 16];          // [b][h][d]
  __shared__ float Zs[4 * 16 * 44];          // [b][d][m] (pad 44: bank + m=39 zero)

  const int t = threadIdx.x;
  const int bbase = blockIdx.x * 4;

  for (int i = t; i < 4 * HH * 16; i += 256) {
    int b = i / (HH * 16), rem = i % (HH * 16);
    int h = rem >> 4, d = rem & 15;
    Hs[i] = (h < HR) ? Hin[((long)(bbase + b) * HR + h) * 16 + d] : 0.f;
  }
  for (int i = t; i < 4 * 39 * 16; i += 256) {
    int b = i / 624, rem = i % 624;
    int m = rem >> 4, d = rem & 15;
    Zs[(b * 16 + d) * 44 + m] = Zin[((long)(bbase + b) * 39 + m) * 16 + d];
  }
  if (t < 64) Zs[t * 44 + 39] = 0.f;  // zero-pad m=39 for b*16+d = t
  __syncthreads();

  const int l = t & 63;
  const int w = t >> 6;
  const int mh6 = (w >> 1) * 6;  // M-half: tiles mh6 .. mh6+6
  const int cg = w & 1;
  const int d = l & 15;
  const int g = l >> 4;
  const int b0l = cg * 2, b1l = cg * 2 + 1;

  const __bf16* wlane = Wg + (l << 3);
  const float* z0base = &Zs[(b0l * 16 + d) * 44];
  const float* z1base = &Zs[(b1l * 16 + d) * 44];
  const float* h0base = &Hs[b0l * HH * 16 + d];
  const float* h1base = &Hs[b1l * HH * 16 + d];

  f32x4 acc[7][2] = {};

  for (int c = 0; c < NCH; ++c) {
    // A-fragments: issue all 7 W loads first (L2 latency cover)
    bf16x8 wf[7];
#pragma unroll
    for (int i = 0; i < 7; ++i)
      wf[i] = *reinterpret_cast<const bf16x8*>(wlane + ((c * 13 + mh6 + i) << 9));

    // B-fragments: X[k, col] = H[h(k), col] * Z[m(k), col], k = 8 consecutive
    int base = c * 32 + g * 8;  // aligned-8 group never crosses h (40 % 8 == 0)
    unsigned h_l = (unsigned)base / 40u;
    unsigned m_l = (unsigned)base - h_l * 40u;
    float h0 = h0base[h_l * 16];
    float h1 = h1base[h_l * 16];
    const float4* zp0 = reinterpret_cast<const float4*>(z0base + m_l);
    const float4* zp1 = reinterpret_cast<const float4*>(z1base + m_l);
    float4 za = zp0[0], zb = zp0[1];
    float4 zc = zp1[0], zd = zp1[1];
    bf16x8 x0, x1;
    x0[0] = (__bf16)(h0 * za.x); x0[1] = (__bf16)(h0 * za.y);
    x0[2] = (__bf16)(h0 * za.z); x0[3] = (__bf16)(h0 * za.w);
    x0[4] = (__bf16)(h0 * zb.x); x0[5] = (__bf16)(h0 * zb.y);
    x0[6] = (__bf16)(h0 * zb.z); x0[7] = (__bf16)(h0 * zb.w);
    x1[0] = (__bf16)(h1 * zc.x); x1[1] = (__bf16)(h1 * zc.y);
    x1[2] = (__bf16)(h1 * zc.z); x1[3] = (__bf16)(h1 * zc.w);
    x1[4] = (__bf16)(h1 * zd.x); x1[5] = (__bf16)(h1 * zd.y);
    x1[6] = (__bf16)(h1 * zd.z); x1[7] = (__bf16)(h1 * zd.w);

#pragma unroll
    for (int i = 0; i < 7; ++i) {
      acc[i][0] = __builtin_amdgcn_mfma_f32_16x16x32_bf16(wf[i], x0, acc[i][0], 0, 0, 0);
      acc[i][1] = __builtin_amdgcn_mfma_f32_16x16x32_bf16(wf[i], x1, acc[i][1], 0, 0, 0);
    }
  }

  // Epilogue: D frag layout col = lane&15 (= d), row = g*4 + r
#pragma unroll
  for (int i = 0; i < 7; ++i) {
    int mt = mh6 + i;
#pragma unroll
    for (int nt = 0; nt < 2; ++nt) {
      int b = bbase + cg * 2 + nt;
#pragma unroll
      for (int r = 0; r < 4; ++r) {
        int o = mt * 16 + g * 4 + r;
        if (o < 200) {
          float x = fmaxf(acc[i][nt][r] + bias[o], 0.f);
          if (SPLIT && o < HHALF) {
            h_next[((long)b * HHALF + o) * 16 + d] = x;
          } else {
            x += __shfl_xor(x, 1);
            x += __shfl_xor(x, 2);
            x += __shfl_xor(x, 4);
            x += __shfl_xor(x, 8);
            if (d == 0) {
              int col = col_offset + o - (SPLIT ? HHALF : 0);
              cin_out[b * 400 + col] = x;
            }
          }
        }
      }
    }
  }
}

// ---------------------------------------------------------------------------
// K4: DNN layer (fp32), 4 batches/block
// ---------------------------------------------------------------------------
template <int IN>
__global__ __launch_bounds__(256) void dnn_kernel(
    const float* __restrict__ x, const float* __restrict__ W,
    const float* __restrict__ bias, float* __restrict__ out) {
  int b0 = blockIdx.x * 4;
  int t = threadIdx.x;
  __shared__ __align__(16) float xs[4 * IN];
  for (int i = t; i < 4 * IN; i += 256) xs[i] = x[(long)b0 * IN + i];
  __syncthreads();
  const float4* xs4 = reinterpret_cast<const float4*>(xs);
  for (int o = t; o < 400; o += 256) {
    const float4* w = reinterpret_cast<const float4*>(W + (long)o * IN);
    float a0 = bias[o], a1 = a0, a2 = a0, a3 = a0;
    for (int k = 0; k < IN / 4; ++k) {
      float4 wv = w[k];
      float4 x0 = xs4[0 * (IN / 4) + k];
      float4 x1 = xs4[1 * (IN / 4) + k];
      float4 x2 = xs4[2 * (IN / 4) + k];
      float4 x3 = xs4[3 * (IN / 4) + k];
      a0 += wv.x * x0.x + wv.y * x0.y + wv.z * x0.z + wv.w * x0.w;
      a1 += wv.x * x1.x + wv.y * x1.y + wv.z * x1.z + wv.w * x1.w;
      a2 += wv.x * x2.x + wv.y * x2.y + wv.z * x2.z + wv.w * x2.w;
      a3 += wv.x * x3.x + wv.y * x3.y + wv.z * x3.z + wv.w * x3.w;
    }
    out[(long)(b0 + 0) * 400 + o] = fmaxf(a0, 0.f);
    out[(long)(b0 + 1) * 400 + o] = fmaxf(a1, 0.f);
    out[(long)(b0 + 2) * 400 + o] = fmaxf(a2, 0.f);
    out[(long)(b0 + 3) * 400 + o] = fmaxf(a3, 0.f);
  }
}

// ---------------------------------------------------------------------------
// K5: final FC + bias-embedding sum
// ---------------------------------------------------------------------------
__global__ __launch_bounds__(256) void final_kernel(
    const float* __restrict__ cin, const float* __restrict__ d1,
    const float* __restrict__ fcW, const float* __restrict__ fcb,
    const float* __restrict__ biassum, float* __restrict__ out) {
  int b = blockIdx.x, t = threadIdx.x;
  float p = 0.f;
  for (int i = t; i < 800; i += 256) {
    float v = (i < 400) ? cin[b * 400 + i] : d1[b * 400 + (i - 400)];
    p += v * fcW[i];
  }
#pragma unroll
  for (int m = 32; m >= 1; m >>= 1) p += __shfl_xor(p, m);
  __shared__ float red[4];
  if ((t & 63) == 0) red[t >> 6] = p;
  __syncthreads();
  if (t == 0) out[b] = red[0] + red[1] + red[2] + red[3] + fcb[0] + biassum[b];
}

// ---------------------------------------------------------------------------
extern "C" void kernel_launch(void* const* d_in, const int* in_sizes, int n_in,
                              void* d_out, int out_size, void* d_ws,
                              size_t ws_size, hipStream_t stream) {
  (void)in_sizes; (void)n_in; (void)out_size; (void)ws_size;
  const int* fid = (const int*)d_in[0];
  const float* fval = (const float*)d_in[1];
  const float* emb = (const float*)d_in[2];
  const float* bias_emb = (const float*)d_in[3];
  const float* cW0 = (const float*)d_in[4];
  const float* cb0 = (const float*)d_in[5];
  const float* cW1 = (const float*)d_in[6];
  const float* cb1 = (const float*)d_in[7];
  const float* cW2 = (const float*)d_in[8];
  const float* cb2 = (const float*)d_in[9];
  const float* dW0 = (const float*)d_in[10];
  const float* db0 = (const float*)d_in[11];
  const float* dW1 = (const float*)d_in[12];
  const float* db1 = (const float*)d_in[13];
  const float* fcW = (const float*)d_in[14];
  const float* fcb = (const float*)d_in[15];
  float* out = (float*)d_out;

  float* ws = (float*)d_ws;
  float* inputs = ws;  ws += B * NF * D;      // [B][39][16] fp32
  float* biassum = ws; ws += B;
  float* h1 = ws;      ws += B * HHALF * D;
  float* h2 = ws;      ws += B * HHALF * D;
  float* cinres = ws;  ws += B * 400;
  float* dd0 = ws;     ws += B * 400;
  float* dd1 = ws;     ws += B * 400;
  __bf16* Wg0 = (__bf16*)ws; ws += (50 * 13 * 64 * 8) / 2;    // 332800 bf16
  __bf16* Wg1 = (__bf16*)ws; ws += (125 * 13 * 64 * 8) / 2;   // 832000 bf16
  __bf16* Wg2 = (__bf16*)ws; ws += (125 * 13 * 64 * 8) / 2;

  gather_kernel<<<B, 256, 0, stream>>>(fid, fval, emb, bias_emb, inputs, biassum);

  prep_w_kernel<<<(50 * 13 * 64 + 255) / 256, 256, 0, stream>>>(cW0, Wg0, 39, 50);
  prep_w_kernel<<<(125 * 13 * 64 + 255) / 256, 256, 0, stream>>>(cW1, Wg1, 100, 125);
  prep_w_kernel<<<(125 * 13 * 64 + 255) / 256, 256, 0, stream>>>(cW2, Wg2, 100, 125);

  cin_mfma_kernel<40, 1><<<B * D / 64, 256, 0, stream>>>(inputs, inputs, Wg0, cb0, h1, cinres, 0);
  cin_mfma_kernel<100, 1><<<B * D / 64, 256, 0, stream>>>(inputs, h1, Wg1, cb1, h2, cinres, 100);
  cin_mfma_kernel<100, 0><<<B * D / 64, 256, 0, stream>>>(inputs, h2, Wg2, cb2, nullptr, cinres, 200);

  dnn_kernel<624><<<B / 4, 256, 0, stream>>>(inputs, dW0, db0, dd0);
  dnn_kernel<400><<<B / 4, 256, 0, stream>>>(dd0, dW1, db1, dd1);

  final_kernel<<<B, 256, 0, stream>>>(cinres, dd1, fcW, fcb, biassum, out);
}

// Round 4
// 317.839 us; speedup vs baseline: 23.4923x; 1.6007x over previous
//
#include <hip/hip_runtime.h>

#define B 2048
#define NF 39
#define D 16

typedef __bf16 bf16x8 __attribute__((ext_vector_type(8)));
typedef float f32x4 __attribute__((ext_vector_type(4)));

// ---------------------------------------------------------------------------
// K1: embedding gather + scale, and bias-embedding row-sum
// ---------------------------------------------------------------------------
__global__ __launch_bounds__(256) void gather_kernel(
    const int* __restrict__ fid, const float* __restrict__ fval,
    const float* __restrict__ emb, const float* __restrict__ bias_emb,
    float* __restrict__ inputs, float* __restrict__ biassum) {
  int b = blockIdx.x;
  __shared__ int ids[NF];
  __shared__ float vals[NF];
  int t = threadIdx.x;
  if (t < NF) { ids[t] = fid[b * NF + t]; vals[t] = fval[b * NF + t]; }
  __syncthreads();
  for (int i = t; i < NF * D; i += 256) {
    int f = i >> 4, d = i & 15;
    inputs[b * NF * D + i] = emb[(long)ids[f] * D + d] * vals[f];
  }
  if (t < 64) {
    float pb = (t < NF) ? bias_emb[ids[t]] * vals[t] : 0.f;
#pragma unroll
    for (int m = 32; m >= 1; m >>= 1) pb += __shfl_xor(pb, m);
    if (t == 0) biassum[b] = pb;
  }
}

// ---------------------------------------------------------------------------
// K2a: pack CIN weights into bf16 MFMA A-fragment layout.
// Wg[((c*13 + mt)*64 + l)*8 + j] = W[o = mt*16 + (l&15)][k = c*32+(l>>4)*8+j]
// with k' = h*40+m padding.
// ---------------------------------------------------------------------------
__global__ void prep_w_kernel(const float* __restrict__ W, __bf16* __restrict__ Wg,
                              int Hreal, int nch) {
  int idx = blockIdx.x * 256 + threadIdx.x;
  int total = nch * 13 * 64;
  if (idx >= total) return;
  int l = idx & 63;
  int mt = (idx >> 6) % 13;
  int c = idx / (13 * 64);
  int o = mt * 16 + (l & 15);
  int kb = c * 32 + ((l >> 4) << 3);
  int rowlen = Hreal * 39;
  bf16x8 v;
#pragma unroll
  for (int j = 0; j < 8; ++j) {
    int k = kb + j;
    int h = k / 40;
    int m = k - h * 40;
    float val = 0.f;
    if (o < 200 && h < Hreal && m < 39) val = W[(long)o * rowlen + h * 39 + m];
    v[j] = (__bf16)val;
  }
  *reinterpret_cast<bf16x8*>(Wg + (long)idx * 8) = v;
}

// ---------------------------------------------------------------------------
// K2b: pack DNN weights: Wd[((c*25 + tt)*64 + l)*8 + j], K padded to nch*32
// ---------------------------------------------------------------------------
__global__ void prep_dnn_w(const float* __restrict__ W, __bf16* __restrict__ Wd,
                           int IN, int nch) {
  int idx = blockIdx.x * 256 + threadIdx.x;
  int total = nch * 25 * 64;
  if (idx >= total) return;
  int l = idx & 63;
  int tt = (idx >> 6) % 25;
  int c = idx / (25 * 64);
  int o = tt * 16 + (l & 15);
  int kb = c * 32 + ((l >> 4) << 3);
  bf16x8 v;
#pragma unroll
  for (int j = 0; j < 8; ++j) {
    int k = kb + j;
    v[j] = (k < IN) ? (__bf16)W[(long)o * IN + k] : (__bf16)0.f;
  }
  *reinterpret_cast<bf16x8*>(Wd + (long)idx * 8) = v;
}

// ---------------------------------------------------------------------------
// K3: CIN layer. Per-wave core, templated on wave id for static indexing.
// (t,f)-pair split: wave W owns pairs p = 13W .. 13W+12, t = p>>2, f = p&3.
// B-frag formed in-register from LDS Hs[h][col], Zt[mblk][col][8] (bf16).
// W-frags from global, register double-buffered. No barriers in K-loop.
// ---------------------------------------------------------------------------
template <int W, int NCH, int SPLIT>
__device__ __forceinline__ void cin_core(
    const __bf16* Hs, const __bf16* Zt, const __bf16* __restrict__ Wg,
    const float* __restrict__ bias, float* __restrict__ h_next,
    float* __restrict__ cin_out, int col_offset, int bbase, int l) {
  constexpr int TLO = (13 * W) >> 2;  // 0,3,6,9
  const int q = l >> 4;
  const int dd = l & 15;
  const __bf16* wl = Wg + l * 8;

  f32x4 acc[13] = {};
  bf16x8 wf[4], wfn[4];
#pragma unroll
  for (int i = 0; i < 4; ++i)
    wf[i] = *reinterpret_cast<const bf16x8*>(wl + (long)((TLO + i) * 64) * 8);

  for (int c = 0; c < NCH; ++c) {
    const bool more = (c + 1 < NCH);
    if (more) {
#pragma unroll
      for (int i = 0; i < 4; ++i)
        wfn[i] = *reinterpret_cast<const bf16x8*>(
            wl + (long)(((c + 1) * 13 + TLO + i) * 64) * 8);
    }
    // per-lane (h, mblk) for this chunk (8-k window never crosses h: 40%8==0)
    int k0 = c * 32 + q * 8;
    int h = (int)((unsigned)k0 / 40u);
    int mb = (k0 - h * 40) >> 3;
    bf16x8 bfr[4];
#pragma unroll
    for (int f = 0; f < 4; ++f) {
      int col = f * 16 + dd;
      bf16x8 z8 = *reinterpret_cast<const bf16x8*>(Zt + (mb * 64 + col) * 8);
      float hv = (float)Hs[h * 64 + col];
      bf16x8 x;
#pragma unroll
      for (int j = 0; j < 8; ++j) x[j] = (__bf16)(hv * (float)z8[j]);
      bfr[f] = x;
    }
#pragma unroll
    for (int i = 0; i < 13; ++i) {
      const int p = 13 * W + i;
      acc[i] = __builtin_amdgcn_mfma_f32_16x16x32_bf16(
          wf[(p >> 2) - TLO], bfr[p & 3], acc[i], 0, 0, 0);
    }
    if (more) {
#pragma unroll
      for (int i = 0; i < 4; ++i) wf[i] = wfn[i];
    }
  }

  // epilogue: D layout col = l&15 (=dd), row = q*4 + r
#pragma unroll
  for (int i = 0; i < 13; ++i) {
    const int p = 13 * W + i;
    const int tt = p >> 2, f = p & 3;
    const int b = bbase + f;
#pragma unroll
    for (int r = 0; r < 4; ++r) {
      int o = tt * 16 + q * 4 + r;
      if (o < 200) {
        float x = fmaxf(acc[i][r] + bias[o], 0.f);
        if (SPLIT && o < 100) {
          h_next[((long)b * 100 + o) * 16 + dd] = x;
        } else {
          x += __shfl_xor(x, 1);
          x += __shfl_xor(x, 2);
          x += __shfl_xor(x, 4);
          x += __shfl_xor(x, 8);
          if (dd == 0) cin_out[b * 400 + col_offset + o - (SPLIT ? 100 : 0)] = x;
        }
      }
    }
  }
}

template <int HR, int NCH, int SPLIT>
__global__ __launch_bounds__(256) void cin_mfma2(
    const float* __restrict__ Zin, const float* __restrict__ Hin,
    const __bf16* __restrict__ Wg, const float* __restrict__ bias,
    float* __restrict__ h_next, float* __restrict__ cin_out, int col_offset) {
  constexpr int HH = (HR == 39) ? 40 : 100;
  __shared__ __bf16 Hs[HH * 64];      // [h][col]
  __shared__ __bf16 Zt[5 * 64 * 8];   // [mblk][col][8]
  const int t = threadIdx.x;
  const int bbase = blockIdx.x * 4;

  for (int i = t; i < HH * 64; i += 256) {
    int h = i >> 6, col = i & 63;
    int b = bbase + (col >> 4), d = col & 15;
    Hs[i] = (h < HR) ? (__bf16)Hin[((long)b * HR + h) * 16 + d] : (__bf16)0.f;
  }
  for (int i = t; i < 5 * 64 * 8; i += 256) {
    int j = i & 7, col = (i >> 3) & 63, mblk = i >> 9;
    int m = mblk * 8 + j;
    int b = bbase + (col >> 4), d = col & 15;
    Zt[i] = (m < NF) ? (__bf16)Zin[((long)b * NF + m) * 16 + d] : (__bf16)0.f;
  }
  __syncthreads();

  const int w = t >> 6, l = t & 63;
  if (w == 0)
    cin_core<0, NCH, SPLIT>(Hs, Zt, Wg, bias, h_next, cin_out, col_offset, bbase, l);
  else if (w == 1)
    cin_core<1, NCH, SPLIT>(Hs, Zt, Wg, bias, h_next, cin_out, col_offset, bbase, l);
  else if (w == 2)
    cin_core<2, NCH, SPLIT>(Hs, Zt, Wg, bias, h_next, cin_out, col_offset, bbase, l);
  else
    cin_core<3, NCH, SPLIT>(Hs, Zt, Wg, bias, h_next, cin_out, col_offset, bbase, l);
}

// ---------------------------------------------------------------------------
// K4: DNN layer via MFMA. Grid = 32 b-groups x 2 M-halves. 256 thr = 4 waves.
// mh0: tiles 0-12 (13), 13 pairs/wave; mh1: tiles 13-24 (12), 12 pairs/wave.
// X staged per chunk to LDS bf16 [buf][kblk][64 b][8], double-buffered.
// ---------------------------------------------------------------------------
template <int IN>
__device__ __forceinline__ void dnn_stage(const float* __restrict__ x,
                                          __bf16* Xs, int bg, int c, int t) {
  int b = t >> 2, kb = t & 3;
  int k0 = c * 32 + kb * 8;
  bf16x8 v;
  if (k0 < IN) {
    const float4* p = reinterpret_cast<const float4*>(x + (long)(bg * 64 + b) * IN + k0);
    float4 a = p[0], bq = p[1];
    v[0] = (__bf16)a.x;  v[1] = (__bf16)a.y;  v[2] = (__bf16)a.z;  v[3] = (__bf16)a.w;
    v[4] = (__bf16)bq.x; v[5] = (__bf16)bq.y; v[6] = (__bf16)bq.z; v[7] = (__bf16)bq.w;
  } else {
#pragma unroll
    for (int j = 0; j < 8; ++j) v[j] = (__bf16)0.f;
  }
  *reinterpret_cast<bf16x8*>(Xs + ((kb * 64 + b) << 3)) = v;
}

template <int W, int MH, int IN, int NCH>
__device__ __forceinline__ void dnn_core(
    const float* __restrict__ x, const __bf16* __restrict__ Wd,
    const float* __restrict__ bias, float* __restrict__ out,
    __bf16* Xs, int bg, int t) {
  constexpr int NP = MH ? 12 : 13;
  constexpr int TLO = MH ? (13 + 3 * W) : ((13 * W) >> 2);  // global tile base
  constexpr int TN = MH ? 3 : 4;
  constexpr int WLO = MH ? (3 * W) : ((13 * W) >> 2);  // wf index base (within-half)
  const int l = t & 63;
  const int q = l >> 4, dd = l & 15;
  const __bf16* wl = Wd + l * 8;

  f32x4 acc[NP] = {};
  bf16x8 wf[TN], wfn[TN];
#pragma unroll
  for (int i = 0; i < TN; ++i)
    wf[i] = *reinterpret_cast<const bf16x8*>(wl + (long)((TLO + i) * 64) * 8);

  dnn_stage<IN>(x, Xs, bg, 0, t);
  __syncthreads();

  for (int c = 0; c < NCH; ++c) {
    __bf16* cur = Xs + (c & 1) * 2048;
    __bf16* nxt = Xs + ((c + 1) & 1) * 2048;
    const bool more = (c + 1 < NCH);
    if (more) {
      dnn_stage<IN>(x, nxt, bg, c + 1, t);
#pragma unroll
      for (int i = 0; i < TN; ++i)
        wfn[i] = *reinterpret_cast<const bf16x8*>(
            wl + (long)(((c + 1) * 25 + TLO + i) * 64) * 8);
    }
    bf16x8 bfr[4];
#pragma unroll
    for (int f = 0; f < 4; ++f)
      bfr[f] = *reinterpret_cast<const bf16x8*>(cur + ((q * 64 + f * 16 + dd) << 3));
#pragma unroll
    for (int i = 0; i < NP; ++i) {
      const int p = NP * W + i;
      const int wfi = (MH ? (p >> 2) : (p >> 2)) - WLO;
      acc[i] = __builtin_amdgcn_mfma_f32_16x16x32_bf16(
          wf[wfi], bfr[p & 3], acc[i], 0, 0, 0);
    }
    __syncthreads();
    if (more) {
#pragma unroll
      for (int i = 0; i < TN; ++i) wf[i] = wfn[i];
    }
  }

#pragma unroll
  for (int i = 0; i < NP; ++i) {
    const int p = NP * W + i;
    const int gt = (MH ? 13 : 0) + (p >> 2);
    const int f = p & 3;
    const int b = bg * 64 + f * 16 + dd;
#pragma unroll
    for (int r = 0; r < 4; ++r) {
      int o = gt * 16 + q * 4 + r;
      out[(long)b * 400 + o] = fmaxf(acc[i][r] + bias[o], 0.f);
    }
  }
}

template <int IN, int NCH>
__global__ __launch_bounds__(256) void dnn_mfma(
    const float* __restrict__ x, const __bf16* __restrict__ Wd,
    const float* __restrict__ bias, float* __restrict__ out) {
  __shared__ __bf16 Xs[2 * 4 * 64 * 8];
  const int blk = blockIdx.x;
  const int bg = blk >> 1, mh = blk & 1;
  const int t = threadIdx.x;
  const int w = t >> 6;
  if (mh == 0) {
    if (w == 0) dnn_core<0, 0, IN, NCH>(x, Wd, bias, out, Xs, bg, t);
    else if (w == 1) dnn_core<1, 0, IN, NCH>(x, Wd, bias, out, Xs, bg, t);
    else if (w == 2) dnn_core<2, 0, IN, NCH>(x, Wd, bias, out, Xs, bg, t);
    else dnn_core<3, 0, IN, NCH>(x, Wd, bias, out, Xs, bg, t);
  } else {
    if (w == 0) dnn_core<0, 1, IN, NCH>(x, Wd, bias, out, Xs, bg, t);
    else if (w == 1) dnn_core<1, 1, IN, NCH>(x, Wd, bias, out, Xs, bg, t);
    else if (w == 2) dnn_core<2, 1, IN, NCH>(x, Wd, bias, out, Xs, bg, t);
    else dnn_core<3, 1, IN, NCH>(x, Wd, bias, out, Xs, bg, t);
  }
}

// ---------------------------------------------------------------------------
// K5: final FC + bias-embedding sum
// ---------------------------------------------------------------------------
__global__ __launch_bounds__(256) void final_kernel(
    const float* __restrict__ cin, const float* __restrict__ d1,
    const float* __restrict__ fcW, const float* __restrict__ fcb,
    const float* __restrict__ biassum, float* __restrict__ out) {
  int b = blockIdx.x, t = threadIdx.x;
  float p = 0.f;
  for (int i = t; i < 800; i += 256) {
    float v = (i < 400) ? cin[b * 400 + i] : d1[b * 400 + (i - 400)];
    p += v * fcW[i];
  }
#pragma unroll
  for (int m = 32; m >= 1; m >>= 1) p += __shfl_xor(p, m);
  __shared__ float red[4];
  if ((t & 63) == 0) red[t >> 6] = p;
  __syncthreads();
  if (t == 0) out[b] = red[0] + red[1] + red[2] + red[3] + fcb[0] + biassum[b];
}

// ---------------------------------------------------------------------------
extern "C" void kernel_launch(void* const* d_in, const int* in_sizes, int n_in,
                              void* d_out, int out_size, void* d_ws,
                              size_t ws_size, hipStream_t stream) {
  (void)in_sizes; (void)n_in; (void)out_size; (void)ws_size;
  const int* fid = (const int*)d_in[0];
  const float* fval = (const float*)d_in[1];
  const float* emb = (const float*)d_in[2];
  const float* bias_emb = (const float*)d_in[3];
  const float* cW0 = (const float*)d_in[4];
  const float* cb0 = (const float*)d_in[5];
  const float* cW1 = (const float*)d_in[6];
  const float* cb1 = (const float*)d_in[7];
  const float* cW2 = (const float*)d_in[8];
  const float* cb2 = (const float*)d_in[9];
  const float* dW0 = (const float*)d_in[10];
  const float* db0 = (const float*)d_in[11];
  const float* dW1 = (const float*)d_in[12];
  const float* db1 = (const float*)d_in[13];
  const float* fcW = (const float*)d_in[14];
  const float* fcb = (const float*)d_in[15];
  float* out = (float*)d_out;

  float* ws = (float*)d_ws;
  float* inputs = ws;  ws += B * NF * D;
  float* biassum = ws; ws += B;
  float* h1 = ws;      ws += B * 100 * D;
  float* h2 = ws;      ws += B * 100 * D;
  float* cinres = ws;  ws += B * 400;
  float* dd0 = ws;     ws += B * 400;
  float* dd1 = ws;     ws += B * 400;
  __bf16* Wg0 = (__bf16*)ws; ws += (50 * 13 * 64 * 8) / 2;
  __bf16* Wg1 = (__bf16*)ws; ws += (125 * 13 * 64 * 8) / 2;
  __bf16* Wg2 = (__bf16*)ws; ws += (125 * 13 * 64 * 8) / 2;
  __bf16* Wd0 = (__bf16*)ws; ws += (20 * 25 * 64 * 8) / 2;
  __bf16* Wd1 = (__bf16*)ws; ws += (13 * 25 * 64 * 8) / 2;

  gather_kernel<<<B, 256, 0, stream>>>(fid, fval, emb, bias_emb, inputs, biassum);

  prep_w_kernel<<<(50 * 13 * 64 + 255) / 256, 256, 0, stream>>>(cW0, Wg0, 39, 50);
  prep_w_kernel<<<(125 * 13 * 64 + 255) / 256, 256, 0, stream>>>(cW1, Wg1, 100, 125);
  prep_w_kernel<<<(125 * 13 * 64 + 255) / 256, 256, 0, stream>>>(cW2, Wg2, 100, 125);
  prep_dnn_w<<<(20 * 25 * 64 + 255) / 256, 256, 0, stream>>>(dW0, Wd0, 624, 20);
  prep_dnn_w<<<(13 * 25 * 64 + 255) / 256, 256, 0, stream>>>(dW1, Wd1, 400, 13);

  cin_mfma2<39, 50, 1><<<B / 4, 256, 0, stream>>>(inputs, inputs, Wg0, cb0, h1, cinres, 0);
  cin_mfma2<100, 125, 1><<<B / 4, 256, 0, stream>>>(inputs, h1, Wg1, cb1, h2, cinres, 100);
  cin_mfma2<100, 125, 0><<<B / 4, 256, 0, stream>>>(inputs, h2, Wg2, cb2, nullptr, cinres, 200);

  dnn_mfma<624, 20><<<64, 256, 0, stream>>>(inputs, Wd0, db0, dd0);
  dnn_mfma<400, 13><<<64, 256, 0, stream>>>(dd0, Wd1, db1, dd1);

  final_kernel<<<B, 256, 0, stream>>>(cinres, dd1, fcW, fcb, biassum, out);
}

// Round 5
// 242.689 us; speedup vs baseline: 30.7669x; 1.3097x over previous
//
#include <hip/hip_runtime.h>

#define B 2048
#define NF 39
#define D 16

typedef __bf16 bf16x8 __attribute__((ext_vector_type(8)));
typedef float f32x4 __attribute__((ext_vector_type(4)));

// ---------------------------------------------------------------------------
// K1: embedding gather + scale, and bias-embedding row-sum
// ---------------------------------------------------------------------------
__global__ __launch_bounds__(256) void gather_kernel(
    const int* __restrict__ fid, const float* __restrict__ fval,
    const float* __restrict__ emb, const float* __restrict__ bias_emb,
    float* __restrict__ inputs, float* __restrict__ biassum) {
  int b = blockIdx.x;
  __shared__ int ids[NF];
  __shared__ float vals[NF];
  int t = threadIdx.x;
  if (t < NF) { ids[t] = fid[b * NF + t]; vals[t] = fval[b * NF + t]; }
  __syncthreads();
  for (int i = t; i < NF * D; i += 256) {
    int f = i >> 4, d = i & 15;
    inputs[b * NF * D + i] = emb[(long)ids[f] * D + d] * vals[f];
  }
  if (t < 64) {
    float pb = (t < NF) ? bias_emb[ids[t]] * vals[t] : 0.f;
#pragma unroll
    for (int m = 32; m >= 1; m >>= 1) pb += __shfl_xor(pb, m);
    if (t == 0) biassum[b] = pb;
  }
}

// ---------------------------------------------------------------------------
// K2a: pack CIN weights into bf16 MFMA A-fragment layout.
// Wg[((c*13 + mt)*64 + l)*8 + j] = W[o = mt*16 + (l&15)][k = c*32+(l>>4)*8+j]
// with k = h*40+m padding; zero outside (o<200, h<Hreal, m<39).
// ---------------------------------------------------------------------------
__global__ void prep_w_kernel(const float* __restrict__ W, __bf16* __restrict__ Wg,
                              int Hreal, int nch) {
  int idx = blockIdx.x * 256 + threadIdx.x;
  int total = nch * 13 * 64;
  if (idx >= total) return;
  int l = idx & 63;
  int mt = (idx >> 6) % 13;
  int c = idx / (13 * 64);
  int o = mt * 16 + (l & 15);
  int kb = c * 32 + ((l >> 4) << 3);
  int rowlen = Hreal * 39;
  bf16x8 v;
#pragma unroll
  for (int j = 0; j < 8; ++j) {
    int k = kb + j;
    int h = k / 40;
    int m = k - h * 40;
    float val = 0.f;
    if (o < 200 && h < Hreal && m < 39) val = W[(long)o * rowlen + h * 39 + m];
    v[j] = (__bf16)val;
  }
  *reinterpret_cast<bf16x8*>(Wg + (long)idx * 8) = v;
}

// ---------------------------------------------------------------------------
// K2b: pack DNN weights: Wd[((c*25 + tt)*64 + l)*8 + j], K padded to nch*32
// ---------------------------------------------------------------------------
__global__ void prep_dnn_w(const float* __restrict__ W, __bf16* __restrict__ Wd,
                           int IN, int nch) {
  int idx = blockIdx.x * 256 + threadIdx.x;
  int total = nch * 25 * 64;
  if (idx >= total) return;
  int l = idx & 63;
  int tt = (idx >> 6) % 25;
  int c = idx / (25 * 64);
  int o = tt * 16 + (l & 15);
  int kb = c * 32 + ((l >> 4) << 3);
  bf16x8 v;
#pragma unroll
  for (int j = 0; j < 8; ++j) {
    int k = kb + j;
    v[j] = (k < IN) ? (__bf16)W[(long)o * IN + k] : (__bf16)0.f;
  }
  *reinterpret_cast<bf16x8*>(Wd + (long)idx * 8) = v;
}

// ---------------------------------------------------------------------------
// K3 v3: CIN layer, LDS-shared X formation.
// Stage = 64 k's. 256 threads form X[64k][64col] (bf16, swizzled) cooperatively
// (16 products each, f32 H/Z from LDS), double-buffered, 1 barrier/stage.
// Wave W owns 13 (tile,f) pairs; per stage: 26 MFMA, 8 bfr ds_read_b128,
// 8 W-frag global loads (reg double-buffered).
// X addr (bytes): col*128 + ((g*16) ^ ((col&7)<<4)), g = k-group 0..7.
// ---------------------------------------------------------------------------
__device__ __forceinline__ void form_x(const float* Hs, const float* Zs,
                                       __bf16* xbuf, int k0, int col) {
  int h = (int)((unsigned)k0 / 40u);
  int m0 = k0 - h * 40;
  float hv = Hs[h * 64 + col];
  const float4* zp = reinterpret_cast<const float4*>(Zs + col * 44 + m0);
  float4 za = zp[0], zb = zp[1];
  bf16x8 xv;
  xv[0] = (__bf16)(hv * za.x); xv[1] = (__bf16)(hv * za.y);
  xv[2] = (__bf16)(hv * za.z); xv[3] = (__bf16)(hv * za.w);
  xv[4] = (__bf16)(hv * zb.x); xv[5] = (__bf16)(hv * zb.y);
  xv[6] = (__bf16)(hv * zb.z); xv[7] = (__bf16)(hv * zb.w);
  int g = (k0 >> 3) & 7;
  *reinterpret_cast<bf16x8*>(
      reinterpret_cast<char*>(xbuf) + col * 128 + ((g * 16) ^ ((col & 7) << 4))) = xv;
}

template <int W, int NST, int SPLIT>
__device__ __forceinline__ void cin_core3(
    const float* Hs, const float* Zs, __bf16* Xs,
    const __bf16* __restrict__ Wg, const float* __restrict__ bias,
    float* __restrict__ h_next, float* __restrict__ cin_out,
    int col_offset, int bbase, int t) {
  constexpr int TLO = (13 * W) >> 2;  // 0,3,6,9
  const int l = t & 63;
  const int q = l >> 4;
  const int dd = l & 15;
  const int colw = t & 63;  // X-form column (== l)
  const __bf16* wl = Wg + l * 8;

  f32x4 acc[13] = {};
  bf16x8 wf[8], wfn[8];
#pragma unroll
  for (int i = 0; i < 4; ++i)
#pragma unroll
    for (int hf = 0; hf < 2; ++hf)
      wf[i * 2 + hf] =
          *reinterpret_cast<const bf16x8*>(wl + (long)((hf * 13 + TLO + i) * 64) * 8);

  // form X for stage 0 into buf0 (k-groups W and W+4)
  form_x(Hs, Zs, Xs, (W) * 8, colw);
  form_x(Hs, Zs, Xs, (W + 4) * 8, colw);
  __syncthreads();

  for (int s = 0; s < NST; ++s) {
    __bf16* xcur = Xs + (s & 1) * (64 * 64);
    __bf16* xnxt = Xs + ((s + 1) & 1) * (64 * 64);
    if (s + 1 < NST) {
      // W prefetch for next stage (chunks 2(s+1), 2(s+1)+1)
#pragma unroll
      for (int i = 0; i < 4; ++i)
#pragma unroll
        for (int hf = 0; hf < 2; ++hf)
          wfn[i * 2 + hf] = *reinterpret_cast<const bf16x8*>(
              wl + (long)((((s + 1) * 2 + hf) * 13 + TLO + i) * 64) * 8);
      // cooperative X formation for next stage
      form_x(Hs, Zs, xnxt, (s + 1) * 64 + W * 8, colw);
      form_x(Hs, Zs, xnxt, (s + 1) * 64 + (W + 4) * 8, colw);
    }
    // B-fragments from current X
    bf16x8 bfr[4][2];
#pragma unroll
    for (int f = 0; f < 4; ++f)
#pragma unroll
      for (int hf = 0; hf < 2; ++hf) {
        int col = f * 16 + dd;
        int g = q + hf * 4;
        bfr[f][hf] = *reinterpret_cast<const bf16x8*>(
            reinterpret_cast<const char*>(xcur) + col * 128 +
            ((g * 16) ^ ((col & 7) << 4)));
      }
#pragma unroll
    for (int i = 0; i < 13; ++i) {
      const int p = 13 * W + i;
      const int ti = (p >> 2) - TLO;
      const int f = p & 3;
      acc[i] = __builtin_amdgcn_mfma_f32_16x16x32_bf16(wf[ti * 2 + 0], bfr[f][0],
                                                       acc[i], 0, 0, 0);
      acc[i] = __builtin_amdgcn_mfma_f32_16x16x32_bf16(wf[ti * 2 + 1], bfr[f][1],
                                                       acc[i], 0, 0, 0);
    }
    __syncthreads();
    if (s + 1 < NST) {
#pragma unroll
      for (int i = 0; i < 8; ++i) wf[i] = wfn[i];
    }
  }

  // epilogue: D layout col = dd, row = q*4 + r
#pragma unroll
  for (int i = 0; i < 13; ++i) {
    const int p = 13 * W + i;
    const int tt = p >> 2, f = p & 3;
    const int b = bbase + f;
#pragma unroll
    for (int r = 0; r < 4; ++r) {
      int o = tt * 16 + q * 4 + r;
      if (o < 200) {
        float x = fmaxf(acc[i][r] + bias[o], 0.f);
        if (SPLIT && o < 100) {
          h_next[((long)b * 100 + o) * 16 + dd] = x;
        } else {
          x += __shfl_xor(x, 1);
          x += __shfl_xor(x, 2);
          x += __shfl_xor(x, 4);
          x += __shfl_xor(x, 8);
          if (dd == 0) cin_out[b * 400 + col_offset + o - (SPLIT ? 100 : 0)] = x;
        }
      }
    }
  }
}

template <int HR, int NST, int SPLIT>
__global__ __launch_bounds__(256, 2) void cin_mfma3(
    const float* __restrict__ Zin, const float* __restrict__ Hin,
    const __bf16* __restrict__ Wg, const float* __restrict__ bias,
    float* __restrict__ h_next, float* __restrict__ cin_out, int col_offset) {
  constexpr int HPAD = (NST * 64 + 39) / 40;  // 40 (layer0) / 101 (layers 1,2)
  __shared__ float Hs[HPAD * 64];   // [h][col], rows >= HR zeroed
  __shared__ float Zs[64 * 44];     // [col][m], m=39..43 pad (39 zeroed)
  __shared__ __bf16 Xs[2 * 64 * 64];  // double-buffered X, swizzled
  const int t = threadIdx.x;
  const int bbase = blockIdx.x * 4;

  for (int i = t; i < HPAD * 64; i += 256) {
    int h = i >> 6, col = i & 63;
    int b = bbase + (col >> 4), d = col & 15;
    Hs[i] = (h < HR) ? Hin[((long)b * HR + h) * 16 + d] : 0.f;
  }
  for (int i = t; i < 64 * 40; i += 256) {
    int col = i / 40, m = i - (i / 40) * 40;
    int b = bbase + (col >> 4), d = col & 15;
    Zs[col * 44 + m] = (m < NF) ? Zin[((long)b * NF + m) * 16 + d] : 0.f;
  }
  __syncthreads();

  const int w = t >> 6;
  if (w == 0)
    cin_core3<0, NST, SPLIT>(Hs, Zs, Xs, Wg, bias, h_next, cin_out, col_offset, bbase, t);
  else if (w == 1)
    cin_core3<1, NST, SPLIT>(Hs, Zs, Xs, Wg, bias, h_next, cin_out, col_offset, bbase, t);
  else if (w == 2)
    cin_core3<2, NST, SPLIT>(Hs, Zs, Xs, Wg, bias, h_next, cin_out, col_offset, bbase, t);
  else
    cin_core3<3, NST, SPLIT>(Hs, Zs, Xs, Wg, bias, h_next, cin_out, col_offset, bbase, t);
}

// ---------------------------------------------------------------------------
// K4: DNN layer via MFMA (unchanged from round 4)
// ---------------------------------------------------------------------------
template <int IN>
__device__ __forceinline__ void dnn_stage(const float* __restrict__ x,
                                          __bf16* Xs, int bg, int c, int t) {
  int b = t >> 2, kb = t & 3;
  int k0 = c * 32 + kb * 8;
  bf16x8 v;
  if (k0 < IN) {
    const float4* p = reinterpret_cast<const float4*>(x + (long)(bg * 64 + b) * IN + k0);
    float4 a = p[0], bq = p[1];
    v[0] = (__bf16)a.x;  v[1] = (__bf16)a.y;  v[2] = (__bf16)a.z;  v[3] = (__bf16)a.w;
    v[4] = (__bf16)bq.x; v[5] = (__bf16)bq.y; v[6] = (__bf16)bq.z; v[7] = (__bf16)bq.w;
  } else {
#pragma unroll
    for (int j = 0; j < 8; ++j) v[j] = (__bf16)0.f;
  }
  *reinterpret_cast<bf16x8*>(Xs + ((kb * 64 + b) << 3)) = v;
}

template <int W, int MH, int IN, int NCH>
__device__ __forceinline__ void dnn_core(
    const float* __restrict__ x, const __bf16* __restrict__ Wd,
    const float* __restrict__ bias, float* __restrict__ out,
    __bf16* Xs, int bg, int t) {
  constexpr int NP = MH ? 12 : 13;
  constexpr int TLO = MH ? (13 + 3 * W) : ((13 * W) >> 2);
  constexpr int TN = MH ? 3 : 4;
  constexpr int WLO = MH ? (3 * W) : ((13 * W) >> 2);
  const int l = t & 63;
  const int q = l >> 4, dd = l & 15;
  const __bf16* wl = Wd + l * 8;

  f32x4 acc[NP] = {};
  bf16x8 wf[TN], wfn[TN];
#pragma unroll
  for (int i = 0; i < TN; ++i)
    wf[i] = *reinterpret_cast<const bf16x8*>(wl + (long)((TLO + i) * 64) * 8);

  dnn_stage<IN>(x, Xs, bg, 0, t);
  __syncthreads();

  for (int c = 0; c < NCH; ++c) {
    __bf16* cur = Xs + (c & 1) * 2048;
    __bf16* nxt = Xs + ((c + 1) & 1) * 2048;
    const bool more = (c + 1 < NCH);
    if (more) {
      dnn_stage<IN>(x, nxt, bg, c + 1, t);
#pragma unroll
      for (int i = 0; i < TN; ++i)
        wfn[i] = *reinterpret_cast<const bf16x8*>(
            wl + (long)(((c + 1) * 25 + TLO + i) * 64) * 8);
    }
    bf16x8 bfr[4];
#pragma unroll
    for (int f = 0; f < 4; ++f)
      bfr[f] = *reinterpret_cast<const bf16x8*>(cur + ((q * 64 + f * 16 + dd) << 3));
#pragma unroll
    for (int i = 0; i < NP; ++i) {
      const int p = NP * W + i;
      const int wfi = (p >> 2) - WLO;
      acc[i] = __builtin_amdgcn_mfma_f32_16x16x32_bf16(wf[wfi], bfr[p & 3], acc[i], 0, 0, 0);
    }
    __syncthreads();
    if (more) {
#pragma unroll
      for (int i = 0; i < TN; ++i) wf[i] = wfn[i];
    }
  }

#pragma unroll
  for (int i = 0; i < NP; ++i) {
    const int p = NP * W + i;
    const int gt = (MH ? 13 : 0) + (p >> 2);
    const int f = p & 3;
    const int b = bg * 64 + f * 16 + dd;
#pragma unroll
    for (int r = 0; r < 4; ++r) {
      int o = gt * 16 + q * 4 + r;
      out[(long)b * 400 + o] = fmaxf(acc[i][r] + bias[o], 0.f);
    }
  }
}

template <int IN, int NCH>
__global__ __launch_bounds__(256) void dnn_mfma(
    const float* __restrict__ x, const __bf16* __restrict__ Wd,
    const float* __restrict__ bias, float* __restrict__ out) {
  __shared__ __bf16 Xs[2 * 4 * 64 * 8];
  const int blk = blockIdx.x;
  const int bg = blk >> 1, mh = blk & 1;
  const int t = threadIdx.x;
  const int w = t >> 6;
  if (mh == 0) {
    if (w == 0) dnn_core<0, 0, IN, NCH>(x, Wd, bias, out, Xs, bg, t);
    else if (w == 1) dnn_core<1, 0, IN, NCH>(x, Wd, bias, out, Xs, bg, t);
    else if (w == 2) dnn_core<2, 0, IN, NCH>(x, Wd, bias, out, Xs, bg, t);
    else dnn_core<3, 0, IN, NCH>(x, Wd, bias, out, Xs, bg, t);
  } else {
    if (w == 0) dnn_core<0, 1, IN, NCH>(x, Wd, bias, out, Xs, bg, t);
    else if (w == 1) dnn_core<1, 1, IN, NCH>(x, Wd, bias, out, Xs, bg, t);
    else if (w == 2) dnn_core<2, 1, IN, NCH>(x, Wd, bias, out, Xs, bg, t);
    else dnn_core<3, 1, IN, NCH>(x, Wd, bias, out, Xs, bg, t);
  }
}

// ---------------------------------------------------------------------------
// K5: final FC + bias-embedding sum
// ---------------------------------------------------------------------------
__global__ __launch_bounds__(256) void final_kernel(
    const float* __restrict__ cin, const float* __restrict__ d1,
    const float* __restrict__ fcW, const float* __restrict__ fcb,
    const float* __restrict__ biassum, float* __restrict__ out) {
  int b = blockIdx.x, t = threadIdx.x;
  float p = 0.f;
  for (int i = t; i < 800; i += 256) {
    float v = (i < 400) ? cin[b * 400 + i] : d1[b * 400 + (i - 400)];
    p += v * fcW[i];
  }
#pragma unroll
  for (int m = 32; m >= 1; m >>= 1) p += __shfl_xor(p, m);
  __shared__ float red[4];
  if ((t & 63) == 0) red[t >> 6] = p;
  __syncthreads();
  if (t == 0) out[b] = red[0] + red[1] + red[2] + red[3] + fcb[0] + biassum[b];
}

// ---------------------------------------------------------------------------
extern "C" void kernel_launch(void* const* d_in, const int* in_sizes, int n_in,
                              void* d_out, int out_size, void* d_ws,
                              size_t ws_size, hipStream_t stream) {
  (void)in_sizes; (void)n_in; (void)out_size; (void)ws_size;
  const int* fid = (const int*)d_in[0];
  const float* fval = (const float*)d_in[1];
  const float* emb = (const float*)d_in[2];
  const float* bias_emb = (const float*)d_in[3];
  const float* cW0 = (const float*)d_in[4];
  const float* cb0 = (const float*)d_in[5];
  const float* cW1 = (const float*)d_in[6];
  const float* cb1 = (const float*)d_in[7];
  const float* cW2 = (const float*)d_in[8];
  const float* cb2 = (const float*)d_in[9];
  const float* dW0 = (const float*)d_in[10];
  const float* db0 = (const float*)d_in[11];
  const float* dW1 = (const float*)d_in[12];
  const float* db1 = (const float*)d_in[13];
  const float* fcW = (const float*)d_in[14];
  const float* fcb = (const float*)d_in[15];
  float* out = (float*)d_out;

  float* ws = (float*)d_ws;
  float* inputs = ws;  ws += B * NF * D;
  float* biassum = ws; ws += B;
  float* h1 = ws;      ws += B * 100 * D;
  float* h2 = ws;      ws += B * 100 * D;
  float* cinres = ws;  ws += B * 400;
  float* dd0 = ws;     ws += B * 400;
  float* dd1 = ws;     ws += B * 400;
  __bf16* Wg0 = (__bf16*)ws; ws += (50 * 13 * 64 * 8) / 2;
  __bf16* Wg1 = (__bf16*)ws; ws += (126 * 13 * 64 * 8) / 2;
  __bf16* Wg2 = (__bf16*)ws; ws += (126 * 13 * 64 * 8) / 2;
  __bf16* Wd0 = (__bf16*)ws; ws += (20 * 25 * 64 * 8) / 2;
  __bf16* Wd1 = (__bf16*)ws; ws += (13 * 25 * 64 * 8) / 2;

  gather_kernel<<<B, 256, 0, stream>>>(fid, fval, emb, bias_emb, inputs, biassum);

  prep_w_kernel<<<(50 * 13 * 64 + 255) / 256, 256, 0, stream>>>(cW0, Wg0, 39, 50);
  prep_w_kernel<<<(126 * 13 * 64 + 255) / 256, 256, 0, stream>>>(cW1, Wg1, 100, 126);
  prep_w_kernel<<<(126 * 13 * 64 + 255) / 256, 256, 0, stream>>>(cW2, Wg2, 100, 126);
  prep_dnn_w<<<(20 * 25 * 64 + 255) / 256, 256, 0, stream>>>(dW0, Wd0, 624, 20);
  prep_dnn_w<<<(13 * 25 * 64 + 255) / 256, 256, 0, stream>>>(dW1, Wd1, 400, 13);

  cin_mfma3<39, 25, 1><<<B / 4, 256, 0, stream>>>(inputs, inputs, Wg0, cb0, h1, cinres, 0);
  cin_mfma3<100, 63, 1><<<B / 4, 256, 0, stream>>>(inputs, h1, Wg1, cb1, h2, cinres, 100);
  cin_mfma3<100, 63, 0><<<B / 4, 256, 0, stream>>>(inputs, h2, Wg2, cb2, nullptr, cinres, 200);

  dnn_mfma<624, 20><<<64, 256, 0, stream>>>(inputs, Wd0, db0, dd0);
  dnn_mfma<400, 13><<<64, 256, 0, stream>>>(dd0, Wd1, db1, dd1);

  final_kernel<<<B, 256, 0, stream>>>(cinres, dd1, fcW, fcb, biassum, out);
}

// Round 6
// 212.685 us; speedup vs baseline: 35.1073x; 1.1411x over previous
//
#include <hip/hip_runtime.h>

#define B 2048
#define NF 39
#define D 16

typedef __bf16 bf16x8 __attribute__((ext_vector_type(8)));
typedef float f32x4 __attribute__((ext_vector_type(4)));

// barrier with LDS-only drain: lets prefetched global loads stay in flight
// across the barrier (compiler still inserts counted vmcnt before first use).
__device__ __forceinline__ void lds_barrier() {
  asm volatile("s_waitcnt lgkmcnt(0)" ::: "memory");
  __builtin_amdgcn_s_barrier();
}

// ---------------------------------------------------------------------------
// K1: embedding gather + scale, and bias-embedding row-sum
// ---------------------------------------------------------------------------
__global__ __launch_bounds__(256) void gather_kernel(
    const int* __restrict__ fid, const float* __restrict__ fval,
    const float* __restrict__ emb, const float* __restrict__ bias_emb,
    float* __restrict__ inputs, float* __restrict__ biassum) {
  int b = blockIdx.x;
  __shared__ int ids[NF];
  __shared__ float vals[NF];
  int t = threadIdx.x;
  if (t < NF) { ids[t] = fid[b * NF + t]; vals[t] = fval[b * NF + t]; }
  __syncthreads();
  for (int i = t; i < NF * D; i += 256) {
    int f = i >> 4, d = i & 15;
    inputs[b * NF * D + i] = emb[(long)ids[f] * D + d] * vals[f];
  }
  if (t < 64) {
    float pb = (t < NF) ? bias_emb[ids[t]] * vals[t] : 0.f;
#pragma unroll
    for (int m = 32; m >= 1; m >>= 1) pb += __shfl_xor(pb, m);
    if (t == 0) biassum[b] = pb;
  }
}

// ---------------------------------------------------------------------------
// K2a: pack CIN weights into bf16 MFMA A-fragment layout.
// Wg[((c*13 + mt)*64 + l)*8 + j] = W[o = mt*16 + (l&15)][k = c*32+(l>>4)*8+j]
// with k = h*40+m padding; zero outside (o<200, h<Hreal, m<39).
// ---------------------------------------------------------------------------
__global__ void prep_w_kernel(const float* __restrict__ W, __bf16* __restrict__ Wg,
                              int Hreal, int nch) {
  int idx = blockIdx.x * 256 + threadIdx.x;
  int total = nch * 13 * 64;
  if (idx >= total) return;
  int l = idx & 63;
  int mt = (idx >> 6) % 13;
  int c = idx / (13 * 64);
  int o = mt * 16 + (l & 15);
  int kb = c * 32 + ((l >> 4) << 3);
  int rowlen = Hreal * 39;
  bf16x8 v;
#pragma unroll
  for (int j = 0; j < 8; ++j) {
    int k = kb + j;
    int h = k / 40;
    int m = k - h * 40;
    float val = 0.f;
    if (o < 200 && h < Hreal && m < 39) val = W[(long)o * rowlen + h * 39 + m];
    v[j] = (__bf16)val;
  }
  *reinterpret_cast<bf16x8*>(Wg + (long)idx * 8) = v;
}

// ---------------------------------------------------------------------------
// K2b: pack DNN weights: Wd[((c*25 + tt)*64 + l)*8 + j], K padded to nch*32
// ---------------------------------------------------------------------------
__global__ void prep_dnn_w(const float* __restrict__ W, __bf16* __restrict__ Wd,
                           int IN, int nch) {
  int idx = blockIdx.x * 256 + threadIdx.x;
  int total = nch * 25 * 64;
  if (idx >= total) return;
  int l = idx & 63;
  int tt = (idx >> 6) % 25;
  int c = idx / (25 * 64);
  int o = tt * 16 + (l & 15);
  int kb = c * 32 + ((l >> 4) << 3);
  bf16x8 v;
#pragma unroll
  for (int j = 0; j < 8; ++j) {
    int k = kb + j;
    v[j] = (k < IN) ? (__bf16)W[(long)o * IN + k] : (__bf16)0.f;
  }
  *reinterpret_cast<bf16x8*>(Wd + (long)idx * 8) = v;
}

// ---------------------------------------------------------------------------
// K3: fused 3-layer CIN. Block = 4 b's (64 cols). h1/h2 live in LDS (Hs).
// Per stage: 8 W global prefetch (reg dbuf, spans barriers), 8 bfr ds_read,
// 2 form_x (shared X build into dbuf LDS), 26 MFMA, lds_barrier (no vmcnt!).
// ---------------------------------------------------------------------------
__device__ __forceinline__ void form_x(const float* Hs, const float* Zs,
                                       __bf16* xbuf, int k0, int col) {
  int h = (int)((unsigned)k0 / 40u);
  int m0 = k0 - h * 40;
  float hv = Hs[h * 64 + col];
  const float4* zp = reinterpret_cast<const float4*>(Zs + col * 44 + m0);
  float4 za = zp[0], zb = zp[1];
  bf16x8 xv;
  xv[0] = (__bf16)(hv * za.x); xv[1] = (__bf16)(hv * za.y);
  xv[2] = (__bf16)(hv * za.z); xv[3] = (__bf16)(hv * za.w);
  xv[4] = (__bf16)(hv * zb.x); xv[5] = (__bf16)(hv * zb.y);
  xv[6] = (__bf16)(hv * zb.z); xv[7] = (__bf16)(hv * zb.w);
  int g = (k0 >> 3) & 7;
  *reinterpret_cast<bf16x8*>(
      reinterpret_cast<char*>(xbuf) + col * 128 + ((g * 16) ^ ((col & 7) << 4))) = xv;
}

template <int NW, int NST, int SPLIT>
__device__ __forceinline__ void cin_layer(
    float* Hs, const float* Zs, __bf16* Xs,
    const __bf16* __restrict__ Wg, const float* __restrict__ bias,
    float* __restrict__ cin_out, int col_offset, int bbase, int t) {
  constexpr int TLO = (13 * NW) >> 2;  // 0,3,6,9
  const int l = t & 63;
  const int q = l >> 4, dd = l & 15;

  f32x4 acc[13] = {};
  bf16x8 wf[8], wfn[8];
  const __bf16* wp = Wg + l * 8 + TLO * 512;
#pragma unroll
  for (int i = 0; i < 4; ++i)
#pragma unroll
    for (int hf = 0; hf < 2; ++hf)
      wf[i * 2 + hf] = *reinterpret_cast<const bf16x8*>(wp + hf * 6656 + i * 512);

  form_x(Hs, Zs, Xs, NW * 8, l);
  form_x(Hs, Zs, Xs, (NW + 4) * 8, l);
  lds_barrier();

  for (int s = 0; s < NST; ++s) {
    __bf16* xcur = Xs + (s & 1) * 4096;
    __bf16* xnxt = Xs + ((s + 1) & 1) * 4096;
    const bool more = (s + 1 < NST);
    if (more) {
      const __bf16* wq = wp + 13312;
#pragma unroll
      for (int i = 0; i < 4; ++i)
#pragma unroll
        for (int hf = 0; hf < 2; ++hf)
          wfn[i * 2 + hf] =
              *reinterpret_cast<const bf16x8*>(wq + hf * 6656 + i * 512);
    }
    bf16x8 bfr[4][2];
#pragma unroll
    for (int f = 0; f < 4; ++f)
#pragma unroll
      for (int hf = 0; hf < 2; ++hf) {
        int col = f * 16 + dd;
        int g = q + hf * 4;
        bfr[f][hf] = *reinterpret_cast<const bf16x8*>(
            reinterpret_cast<const char*>(xcur) + col * 128 +
            ((g * 16) ^ ((col & 7) << 4)));
      }
    if (more) {
      form_x(Hs, Zs, xnxt, (s + 1) * 64 + NW * 8, l);
      form_x(Hs, Zs, xnxt, (s + 1) * 64 + (NW + 4) * 8, l);
    }
    __builtin_amdgcn_s_setprio(1);
#pragma unroll
    for (int i = 0; i < 13; ++i) {
      const int p = 13 * NW + i;
      const int ti = (p >> 2) - TLO;
      const int f = p & 3;
      acc[i] = __builtin_amdgcn_mfma_f32_16x16x32_bf16(wf[ti * 2 + 0], bfr[f][0],
                                                       acc[i], 0, 0, 0);
      acc[i] = __builtin_amdgcn_mfma_f32_16x16x32_bf16(wf[ti * 2 + 1], bfr[f][1],
                                                       acc[i], 0, 0, 0);
    }
    __builtin_amdgcn_s_setprio(0);
    lds_barrier();
    if (more) {
#pragma unroll
      for (int i = 0; i < 8; ++i) wf[i] = wfn[i];
      wp += 13312;
    }
  }

  // epilogue: D layout col = dd, row = q*4 + r
#pragma unroll
  for (int i = 0; i < 13; ++i) {
    const int p = 13 * NW + i;
    const int tt = p >> 2, f = p & 3;
    const int b = bbase + f;
#pragma unroll
    for (int r = 0; r < 4; ++r) {
      int o = tt * 16 + q * 4 + r;
      if (o < 200) {
        float x = fmaxf(acc[i][r] + bias[o], 0.f);
        if (SPLIT && o < 100) {
          Hs[o * 64 + f * 16 + dd] = x;  // h_next stays in LDS
        } else {
          x += __shfl_xor(x, 1);
          x += __shfl_xor(x, 2);
          x += __shfl_xor(x, 4);
          x += __shfl_xor(x, 8);
          if (dd == 0) cin_out[b * 400 + col_offset + o - (SPLIT ? 100 : 0)] = x;
        }
      }
    }
  }
  lds_barrier();
}

template <int NW>
__device__ __forceinline__ void cin_all(
    float* Hs, const float* Zs, __bf16* Xs, const __bf16* Wg0,
    const __bf16* Wg1, const __bf16* Wg2, const float* cb0, const float* cb1,
    const float* cb2, float* cinres, int bbase, int t) {
  cin_layer<NW, 25, 1>(Hs, Zs, Xs, Wg0, cb0, cinres, 0, bbase, t);
  cin_layer<NW, 63, 1>(Hs, Zs, Xs, Wg1, cb1, cinres, 100, bbase, t);
  cin_layer<NW, 63, 0>(Hs, Zs, Xs, Wg2, cb2, cinres, 200, bbase, t);
}

__global__ __launch_bounds__(256, 2) void cin_fused(
    const float* __restrict__ Zin, const __bf16* __restrict__ Wg0,
    const __bf16* __restrict__ Wg1, const __bf16* __restrict__ Wg2,
    const float* __restrict__ cb0, const float* __restrict__ cb1,
    const float* __restrict__ cb2, float* __restrict__ cinres) {
  __shared__ float Hs[101 * 64];    // [h][col]; layer0 uses rows 0..40 as Z^T
  __shared__ float Zs[64 * 44];     // [col][m], m=39 zero pad
  __shared__ __bf16 Xs[2 * 64 * 64];  // double-buffered X, swizzled
  const int t = threadIdx.x;
  const int bbase = blockIdx.x * 4;

  for (int i = t; i < 64 * 40; i += 256) {
    int col = i / 40, m = i - (i / 40) * 40;
    int b = bbase + (col >> 4), d = col & 15;
    Zs[col * 44 + m] = (m < NF) ? Zin[((long)b * NF + m) * 16 + d] : 0.f;
  }
  for (int i = t; i < 41 * 64; i += 256) {
    int h = i >> 6, col = i & 63;
    int b = bbase + (col >> 4), d = col & 15;
    Hs[i] = (h < NF) ? Zin[((long)b * NF + h) * 16 + d] : 0.f;
  }
  if (t < 64) Hs[100 * 64 + t] = 0.f;  // pad row for layers 1/2
  __syncthreads();

  const int w = t >> 6;
  if (w == 0) cin_all<0>(Hs, Zs, Xs, Wg0, Wg1, Wg2, cb0, cb1, cb2, cinres, bbase, t);
  else if (w == 1) cin_all<1>(Hs, Zs, Xs, Wg0, Wg1, Wg2, cb0, cb1, cb2, cinres, bbase, t);
  else if (w == 2) cin_all<2>(Hs, Zs, Xs, Wg0, Wg1, Wg2, cb0, cb1, cb2, cinres, bbase, t);
  else cin_all<3>(Hs, Zs, Xs, Wg0, Wg1, Wg2, cb0, cb1, cb2, cinres, bbase, t);
}

// ---------------------------------------------------------------------------
// K4: DNN via MFMA. Grid = 32 bg x 4 tile-groups (6,6,6,7 tiles). 4 waves.
// Raw lds_barrier + issue-early/write-late X staging (T14).
// ---------------------------------------------------------------------------
template <int IN>
__device__ __forceinline__ void dnn_stage_load(const float* __restrict__ x,
                                               int bg, int c, int t,
                                               float4& a, float4& b2) {
  int b = t >> 2, kb = t & 3;
  int k0 = c * 32 + kb * 8;
  if (k0 < IN) {
    const float4* p =
        reinterpret_cast<const float4*>(x + (long)(bg * 64 + b) * IN + k0);
    a = p[0];
    b2 = p[1];
  } else {
    a = make_float4(0.f, 0.f, 0.f, 0.f);
    b2 = make_float4(0.f, 0.f, 0.f, 0.f);
  }
}

__device__ __forceinline__ void dnn_stage_write(__bf16* Xs, int t, float4 a,
                                                float4 b2) {
  int b = t >> 2, kb = t & 3;
  bf16x8 v;
  v[0] = (__bf16)a.x;  v[1] = (__bf16)a.y;  v[2] = (__bf16)a.z;  v[3] = (__bf16)a.w;
  v[4] = (__bf16)b2.x; v[5] = (__bf16)b2.y; v[6] = (__bf16)b2.z; v[7] = (__bf16)b2.w;
  *reinterpret_cast<bf16x8*>(Xs + ((kb * 64 + b) << 3)) = v;
}

template <int W, int TG, int IN, int NCH>
__device__ __forceinline__ void dnn_core(
    const float* __restrict__ x, const __bf16* __restrict__ Wd,
    const float* __restrict__ bias, float* __restrict__ out, __bf16* Xs,
    int bg, int t) {
  constexpr int NT = (TG == 3) ? 7 : 6;
  constexpr int TGB = TG * 6;
  constexpr int PLO = NT * W;
  constexpr int TLO = PLO >> 2;
  constexpr int TN = ((PLO + NT - 1) >> 2) - TLO + 1;
  const int l = t & 63;
  const int q = l >> 4, dd = l & 15;
  const __bf16* wl = Wd + l * 8;

  f32x4 acc[NT] = {};
  bf16x8 wf[TN], wfn[TN];
#pragma unroll
  for (int i = 0; i < TN; ++i)
    wf[i] = *reinterpret_cast<const bf16x8*>(wl + (long)((TGB + TLO + i) * 64) * 8);

  float4 ra, rb;
  dnn_stage_load<IN>(x, bg, 0, t, ra, rb);
  dnn_stage_write(Xs, t, ra, rb);
  lds_barrier();

  for (int c = 0; c < NCH; ++c) {
    __bf16* cur = Xs + (c & 1) * 2048;
    __bf16* nxt = Xs + ((c + 1) & 1) * 2048;
    const bool more = (c + 1 < NCH);
    if (more) {
      dnn_stage_load<IN>(x, bg, c + 1, t, ra, rb);
#pragma unroll
      for (int i = 0; i < TN; ++i)
        wfn[i] = *reinterpret_cast<const bf16x8*>(
            wl + (long)(((c + 1) * 25 + TGB + TLO + i) * 64) * 8);
    }
    bf16x8 bfr[4];
#pragma unroll
    for (int f = 0; f < 4; ++f)
      bfr[f] = *reinterpret_cast<const bf16x8*>(cur + ((q * 64 + f * 16 + dd) << 3));
    __builtin_amdgcn_s_setprio(1);
#pragma unroll
    for (int i = 0; i < NT; ++i) {
      const int p = PLO + i;
      acc[i] = __builtin_amdgcn_mfma_f32_16x16x32_bf16(wf[(p >> 2) - TLO],
                                                       bfr[p & 3], acc[i], 0, 0, 0);
    }
    __builtin_amdgcn_s_setprio(0);
    if (more) dnn_stage_write(nxt, t, ra, rb);
    lds_barrier();
    if (more) {
#pragma unroll
      for (int i = 0; i < TN; ++i) wf[i] = wfn[i];
    }
  }

#pragma unroll
  for (int i = 0; i < NT; ++i) {
    const int p = PLO + i;
    const int gt = TGB + (p >> 2);
    const int f = p & 3;
    const int b = bg * 64 + f * 16 + dd;
#pragma unroll
    for (int r = 0; r < 4; ++r) {
      int o = gt * 16 + q * 4 + r;
      out[(long)b * 400 + o] = fmaxf(acc[i][r] + bias[o], 0.f);
    }
  }
}

template <int IN, int NCH>
__global__ __launch_bounds__(256) void dnn_mfma(
    const float* __restrict__ x, const __bf16* __restrict__ Wd,
    const float* __restrict__ bias, float* __restrict__ out) {
  __shared__ __bf16 Xs[2 * 4 * 64 * 8];
  const int blk = blockIdx.x;
  const int bg = blk >> 2, tg = blk & 3;
  const int t = threadIdx.x;
  const int w = t >> 6;
#define DNN_DISPATCH(TGV)                                                     \
  if (w == 0) dnn_core<0, TGV, IN, NCH>(x, Wd, bias, out, Xs, bg, t);         \
  else if (w == 1) dnn_core<1, TGV, IN, NCH>(x, Wd, bias, out, Xs, bg, t);    \
  else if (w == 2) dnn_core<2, TGV, IN, NCH>(x, Wd, bias, out, Xs, bg, t);    \
  else dnn_core<3, TGV, IN, NCH>(x, Wd, bias, out, Xs, bg, t);
  if (tg == 0) { DNN_DISPATCH(0) }
  else if (tg == 1) { DNN_DISPATCH(1) }
  else if (tg == 2) { DNN_DISPATCH(2) }
  else { DNN_DISPATCH(3) }
#undef DNN_DISPATCH
}

// ---------------------------------------------------------------------------
// K5: final FC + bias-embedding sum
// ---------------------------------------------------------------------------
__global__ __launch_bounds__(256) void final_kernel(
    const float* __restrict__ cin, const float* __restrict__ d1,
    const float* __restrict__ fcW, const float* __restrict__ fcb,
    const float* __restrict__ biassum, float* __restrict__ out) {
  int b = blockIdx.x, t = threadIdx.x;
  float p = 0.f;
  for (int i = t; i < 800; i += 256) {
    float v = (i < 400) ? cin[b * 400 + i] : d1[b * 400 + (i - 400)];
    p += v * fcW[i];
  }
#pragma unroll
  for (int m = 32; m >= 1; m >>= 1) p += __shfl_xor(p, m);
  __shared__ float red[4];
  if ((t & 63) == 0) red[t >> 6] = p;
  __syncthreads();
  if (t == 0) out[b] = red[0] + red[1] + red[2] + red[3] + fcb[0] + biassum[b];
}

// ---------------------------------------------------------------------------
extern "C" void kernel_launch(void* const* d_in, const int* in_sizes, int n_in,
                              void* d_out, int out_size, void* d_ws,
                              size_t ws_size, hipStream_t stream) {
  (void)in_sizes; (void)n_in; (void)out_size; (void)ws_size;
  const int* fid = (const int*)d_in[0];
  const float* fval = (const float*)d_in[1];
  const float* emb = (const float*)d_in[2];
  const float* bias_emb = (const float*)d_in[3];
  const float* cW0 = (const float*)d_in[4];
  const float* cb0 = (const float*)d_in[5];
  const float* cW1 = (const float*)d_in[6];
  const float* cb1 = (const float*)d_in[7];
  const float* cW2 = (const float*)d_in[8];
  const float* cb2 = (const float*)d_in[9];
  const float* dW0 = (const float*)d_in[10];
  const float* db0 = (const float*)d_in[11];
  const float* dW1 = (const float*)d_in[12];
  const float* db1 = (const float*)d_in[13];
  const float* fcW = (const float*)d_in[14];
  const float* fcb = (const float*)d_in[15];
  float* out = (float*)d_out;

  float* ws = (float*)d_ws;
  float* inputs = ws;  ws += B * NF * D;
  float* biassum = ws; ws += B;
  float* cinres = ws;  ws += B * 400;
  float* dd0 = ws;     ws += B * 400;
  float* dd1 = ws;     ws += B * 400;
  __bf16* Wg0 = (__bf16*)ws; ws += (50 * 13 * 64 * 8) / 2;
  __bf16* Wg1 = (__bf16*)ws; ws += (126 * 13 * 64 * 8) / 2;
  __bf16* Wg2 = (__bf16*)ws; ws += (126 * 13 * 64 * 8) / 2;
  __bf16* Wd0 = (__bf16*)ws; ws += (20 * 25 * 64 * 8) / 2;
  __bf16* Wd1 = (__bf16*)ws; ws += (13 * 25 * 64 * 8) / 2;

  gather_kernel<<<B, 256, 0, stream>>>(fid, fval, emb, bias_emb, inputs, biassum);

  prep_w_kernel<<<(50 * 13 * 64 + 255) / 256, 256, 0, stream>>>(cW0, Wg0, 39, 50);
  prep_w_kernel<<<(126 * 13 * 64 + 255) / 256, 256, 0, stream>>>(cW1, Wg1, 100, 126);
  prep_w_kernel<<<(126 * 13 * 64 + 255) / 256, 256, 0, stream>>>(cW2, Wg2, 100, 126);
  prep_dnn_w<<<(20 * 25 * 64 + 255) / 256, 256, 0, stream>>>(dW0, Wd0, 624, 20);
  prep_dnn_w<<<(13 * 25 * 64 + 255) / 256, 256, 0, stream>>>(dW1, Wd1, 400, 13);

  cin_fused<<<B / 4, 256, 0, stream>>>(inputs, Wg0, Wg1, Wg2, cb0, cb1, cb2, cinres);

  dnn_mfma<624, 20><<<128, 256, 0, stream>>>(inputs, Wd0, db0, dd0);
  dnn_mfma<400, 13><<<128, 256, 0, stream>>>(dd0, Wd1, db1, dd1);

  final_kernel<<<B, 256, 0, stream>>>(cinres, dd1, fcW, fcb, biassum, out);
}

// Round 8
// 208.586 us; speedup vs baseline: 35.7971x; 1.0196x over previous
//
#include <hip/hip_runtime.h>

#define B 2048
#define NF 39
#define D 16

typedef __bf16 bf16x8 __attribute__((ext_vector_type(8)));
typedef float f32x4 __attribute__((ext_vector_type(4)));
typedef float f32x8 __attribute__((ext_vector_type(8)));

// barrier with LDS-only drain: prefetched global loads stay in flight.
__device__ __forceinline__ void lds_barrier() {
  asm volatile("s_waitcnt lgkmcnt(0)" ::: "memory");
  __builtin_amdgcn_s_barrier();
}

// ---------------------------------------------------------------------------
// K1: embedding gather + scale, and bias-embedding row-sum
// ---------------------------------------------------------------------------
__global__ __launch_bounds__(256) void gather_kernel(
    const int* __restrict__ fid, const float* __restrict__ fval,
    const float* __restrict__ emb, const float* __restrict__ bias_emb,
    float* __restrict__ inputs, float* __restrict__ biassum) {
  int b = blockIdx.x;
  __shared__ int ids[NF];
  __shared__ float vals[NF];
  int t = threadIdx.x;
  if (t < NF) { ids[t] = fid[b * NF + t]; vals[t] = fval[b * NF + t]; }
  __syncthreads();
  for (int i = t; i < NF * D; i += 256) {
    int f = i >> 4, d = i & 15;
    inputs[b * NF * D + i] = emb[(long)ids[f] * D + d] * vals[f];
  }
  if (t < 64) {
    float pb = (t < NF) ? bias_emb[ids[t]] * vals[t] : 0.f;
#pragma unroll
    for (int m = 32; m >= 1; m >>= 1) pb += __shfl_xor(pb, m);
    if (t == 0) biassum[b] = pb;
  }
}

// ---------------------------------------------------------------------------
// K2: fused weight prep (3 CIN + 2 DNN pack jobs in one launch).
// CIN layout (r6-proven): Wg[((c*13 + mt)*64 + l)*8 + j],
//   value = W[o = mt*16+(l&15)][k = c*32+(l>>4)*8+j], k = h*40+m padding.
// DNN layout: Wd[((c*25 + tt)*64 + l)*8 + j], K padded to nch*32.
// ---------------------------------------------------------------------------
__device__ __forceinline__ void prep_cin_one(const float* __restrict__ W,
                                             __bf16* __restrict__ Wg,
                                             int Hreal, int idx) {
  int l = idx & 63;
  int mt = (idx >> 6) % 13;
  int c = idx / (13 * 64);
  int o = mt * 16 + (l & 15);
  int kb = c * 32 + ((l >> 4) << 3);
  int rowlen = Hreal * 39;
  bf16x8 v;
#pragma unroll
  for (int j = 0; j < 8; ++j) {
    int k = kb + j;
    int h = k / 40;
    int m = k - h * 40;
    float val = 0.f;
    if (o < 200 && h < Hreal && m < 39) val = W[(long)o * rowlen + h * 39 + m];
    v[j] = (__bf16)val;
  }
  *reinterpret_cast<bf16x8*>(Wg + (long)idx * 8) = v;
}

__device__ __forceinline__ void prep_dnn_one(const float* __restrict__ W,
                                             __bf16* __restrict__ Wd,
                                             int IN, int idx) {
  int l = idx & 63;
  int tt = (idx >> 6) % 25;
  int c = idx / (25 * 64);
  int o = tt * 16 + (l & 15);
  int kb = c * 32 + ((l >> 4) << 3);
  bf16x8 v;
#pragma unroll
  for (int j = 0; j < 8; ++j) {
    int k = kb + j;
    v[j] = (k < IN) ? (__bf16)W[(long)o * IN + k] : (__bf16)0.f;
  }
  *reinterpret_cast<bf16x8*>(Wd + (long)idx * 8) = v;
}

#define PREP_T0 (50 * 13 * 64)
#define PREP_T12 (126 * 13 * 64)
#define PREP_T3 (20 * 25 * 64)
#define PREP_T4 (13 * 25 * 64)
#define PREP_TOTAL (PREP_T0 + 2 * PREP_T12 + PREP_T3 + PREP_T4)

__global__ void prep_all(const float* __restrict__ cW0, const float* __restrict__ cW1,
                         const float* __restrict__ cW2, const float* __restrict__ dW0,
                         const float* __restrict__ dW1, __bf16* __restrict__ Wg0,
                         __bf16* __restrict__ Wg1, __bf16* __restrict__ Wg2,
                         __bf16* __restrict__ Wd0, __bf16* __restrict__ Wd1) {
  int idx = blockIdx.x * 256 + threadIdx.x;
  if (idx < PREP_T0) { prep_cin_one(cW0, Wg0, 39, idx); return; }
  idx -= PREP_T0;
  if (idx < PREP_T12) { prep_cin_one(cW1, Wg1, 100, idx); return; }
  idx -= PREP_T12;
  if (idx < PREP_T12) { prep_cin_one(cW2, Wg2, 100, idx); return; }
  idx -= PREP_T12;
  if (idx < PREP_T3) { prep_dnn_one(dW0, Wd0, 624, idx); return; }
  idx -= PREP_T3;
  if (idx < PREP_T4) prep_dnn_one(dW1, Wd1, 400, idx);
}

// ---------------------------------------------------------------------------
// K3: fused 3-layer CIN. Block = 4 b's (64 cols). h1/h2 live in LDS (Hs).
// Z-column (40 floats) lives in REGISTERS (five f32x8, compile-time indexed
// via wave-uniform switch) -> form_x = 1 LDS b32 read + 1 b128 write only.
// W-frags global->reg double-buffered; 1 lgkm-only barrier per stage.
// ---------------------------------------------------------------------------
#define MUL8(ZV)                                                         \
  {                                                                      \
    xv[0] = (__bf16)(hv * ZV[0]); xv[1] = (__bf16)(hv * ZV[1]);          \
    xv[2] = (__bf16)(hv * ZV[2]); xv[3] = (__bf16)(hv * ZV[3]);          \
    xv[4] = (__bf16)(hv * ZV[4]); xv[5] = (__bf16)(hv * ZV[5]);          \
    xv[6] = (__bf16)(hv * ZV[6]); xv[7] = (__bf16)(hv * ZV[7]);          \
  }

__device__ __forceinline__ void form_x(const float* Hs, f32x8 z0, f32x8 z1,
                                       f32x8 z2, f32x8 z3, f32x8 z4,
                                       __bf16* xbuf, int k0, int col) {
  int h = (int)((unsigned)k0 / 40u);
  int m3 = (k0 - h * 40) >> 3;  // 0..4, wave-uniform (k0 uniform per wave)
  float hv = Hs[h * 64 + col];
  bf16x8 xv;
  switch (m3) {
    case 0: MUL8(z0); break;
    case 1: MUL8(z1); break;
    case 2: MUL8(z2); break;
    case 3: MUL8(z3); break;
    default: MUL8(z4); break;
  }
  int g = (k0 >> 3) & 7;
  *reinterpret_cast<bf16x8*>(
      reinterpret_cast<char*>(xbuf) + col * 128 + ((g * 16) ^ ((col & 7) << 4))) = xv;
}

template <int NW, int NST, int SPLIT>
__device__ __forceinline__ void cin_layer(
    float* Hs, f32x8 z0, f32x8 z1, f32x8 z2, f32x8 z3, f32x8 z4, __bf16* Xs,
    const __bf16* __restrict__ Wg, const float* __restrict__ bias,
    float* __restrict__ cin_out, int col_offset, int bbase, int t) {
  constexpr int TLO = (13 * NW) >> 2;  // 0,3,6,9
  const int l = t & 63;
  const int q = l >> 4, dd = l & 15;

  f32x4 acc[13] = {};
  bf16x8 wf[8], wfn[8];
  const __bf16* wp = Wg + l * 8 + TLO * 512;
#pragma unroll
  for (int i = 0; i < 4; ++i)
#pragma unroll
    for (int hf = 0; hf < 2; ++hf)
      wf[i * 2 + hf] = *reinterpret_cast<const bf16x8*>(wp + hf * 6656 + i * 512);

  form_x(Hs, z0, z1, z2, z3, z4, Xs, NW * 8, l);
  form_x(Hs, z0, z1, z2, z3, z4, Xs, (NW + 4) * 8, l);
  lds_barrier();

  for (int s = 0; s < NST; ++s) {
    __bf16* xcur = Xs + (s & 1) * 4096;
    __bf16* xnxt = Xs + ((s + 1) & 1) * 4096;
    const bool more = (s + 1 < NST);
    if (more) {
      const __bf16* wq = wp + 13312;
#pragma unroll
      for (int i = 0; i < 4; ++i)
#pragma unroll
        for (int hf = 0; hf < 2; ++hf)
          wfn[i * 2 + hf] =
              *reinterpret_cast<const bf16x8*>(wq + hf * 6656 + i * 512);
    }
    bf16x8 bfr[4][2];
#pragma unroll
    for (int f = 0; f < 4; ++f)
#pragma unroll
      for (int hf = 0; hf < 2; ++hf) {
        int col = f * 16 + dd;
        int g = q + hf * 4;
        bfr[f][hf] = *reinterpret_cast<const bf16x8*>(
            reinterpret_cast<const char*>(xcur) + col * 128 +
            ((g * 16) ^ ((col & 7) << 4)));
      }
    if (more) {
      form_x(Hs, z0, z1, z2, z3, z4, xnxt, (s + 1) * 64 + NW * 8, l);
      form_x(Hs, z0, z1, z2, z3, z4, xnxt, (s + 1) * 64 + (NW + 4) * 8, l);
    }
    __builtin_amdgcn_s_setprio(1);
#pragma unroll
    for (int i = 0; i < 13; ++i) {
      const int p = 13 * NW + i;
      const int ti = (p >> 2) - TLO;
      const int f = p & 3;
      acc[i] = __builtin_amdgcn_mfma_f32_16x16x32_bf16(wf[ti * 2 + 0], bfr[f][0],
                                                       acc[i], 0, 0, 0);
      acc[i] = __builtin_amdgcn_mfma_f32_16x16x32_bf16(wf[ti * 2 + 1], bfr[f][1],
                                                       acc[i], 0, 0, 0);
    }
    __builtin_amdgcn_s_setprio(0);
    lds_barrier();
    if (more) {
#pragma unroll
      for (int i = 0; i < 8; ++i) wf[i] = wfn[i];
      wp += 13312;
    }
  }

  // epilogue: D layout col = dd, row = q*4 + r
#pragma unroll
  for (int i = 0; i < 13; ++i) {
    const int p = 13 * NW + i;
    const int tt = p >> 2, f = p & 3;
    const int b = bbase + f;
#pragma unroll
    for (int r = 0; r < 4; ++r) {
      int o = tt * 16 + q * 4 + r;
      if (o < 200) {
        float x = fmaxf(acc[i][r] + bias[o], 0.f);
        if (SPLIT && o < 100) {
          Hs[o * 64 + f * 16 + dd] = x;  // h_next stays in LDS
        } else {
          x += __shfl_xor(x, 1);
          x += __shfl_xor(x, 2);
          x += __shfl_xor(x, 4);
          x += __shfl_xor(x, 8);
          if (dd == 0) cin_out[b * 400 + col_offset + o - (SPLIT ? 100 : 0)] = x;
        }
      }
    }
  }
  lds_barrier();
}

template <int NW>
__device__ __forceinline__ void cin_all(
    float* Hs, f32x8 z0, f32x8 z1, f32x8 z2, f32x8 z3, f32x8 z4, __bf16* Xs,
    const __bf16* Wg0, const __bf16* Wg1, const __bf16* Wg2, const float* cb0,
    const float* cb1, const float* cb2, float* cinres, int bbase, int t) {
  cin_layer<NW, 25, 1>(Hs, z0, z1, z2, z3, z4, Xs, Wg0, cb0, cinres, 0, bbase, t);
  cin_layer<NW, 63, 1>(Hs, z0, z1, z2, z3, z4, Xs, Wg1, cb1, cinres, 100, bbase, t);
  cin_layer<NW, 63, 0>(Hs, z0, z1, z2, z3, z4, Xs, Wg2, cb2, cinres, 200, bbase, t);
}

__global__ __launch_bounds__(256, 2) void cin_fused(
    const float* __restrict__ Zin, const __bf16* __restrict__ Wg0,
    const __bf16* __restrict__ Wg1, const __bf16* __restrict__ Wg2,
    const float* __restrict__ cb0, const float* __restrict__ cb1,
    const float* __restrict__ cb2, float* __restrict__ cinres) {
  __shared__ float Hs[101 * 64];      // [h][col]; layer0 rows 0..40 = Z^T
  __shared__ __bf16 Xs[2 * 64 * 64];  // double-buffered X, swizzled
  const int t = threadIdx.x;
  const int bbase = blockIdx.x * 4;

  // Z column (40 values) -> registers, compile-time indexed
  f32x8 z0, z1, z2, z3, z4;
  {
    int col = t & 63;
    int b = bbase + (col >> 4), d = col & 15;
    const float* zp = Zin + (long)b * NF * 16 + d;
#pragma unroll
    for (int j = 0; j < 8; ++j) z0[j] = zp[j * 16];
#pragma unroll
    for (int j = 0; j < 8; ++j) z1[j] = zp[(8 + j) * 16];
#pragma unroll
    for (int j = 0; j < 8; ++j) z2[j] = zp[(16 + j) * 16];
#pragma unroll
    for (int j = 0; j < 8; ++j) z3[j] = zp[(24 + j) * 16];
#pragma unroll
    for (int j = 0; j < 7; ++j) z4[j] = zp[(32 + j) * 16];
    z4[7] = 0.f;
  }

  for (int i = t; i < 41 * 64; i += 256) {
    int h = i >> 6, col = i & 63;
    int b = bbase + (col >> 4), d = col & 15;
    Hs[i] = (h < NF) ? Zin[((long)b * NF + h) * 16 + d] : 0.f;
  }
  if (t < 64) Hs[100 * 64 + t] = 0.f;  // pad row for layers 1/2
  __syncthreads();

  const int w = t >> 6;
  if (w == 0)
    cin_all<0>(Hs, z0, z1, z2, z3, z4, Xs, Wg0, Wg1, Wg2, cb0, cb1, cb2, cinres, bbase, t);
  else if (w == 1)
    cin_all<1>(Hs, z0, z1, z2, z3, z4, Xs, Wg0, Wg1, Wg2, cb0, cb1, cb2, cinres, bbase, t);
  else if (w == 2)
    cin_all<2>(Hs, z0, z1, z2, z3, z4, Xs, Wg0, Wg1, Wg2, cb0, cb1, cb2, cinres, bbase, t);
  else
    cin_all<3>(Hs, z0, z1, z2, z3, z4, Xs, Wg0, Wg1, Wg2, cb0, cb1, cb2, cinres, bbase, t);
}

// ---------------------------------------------------------------------------
// K4: DNN via MFMA. Grid = 32 bg x 4 tile-groups (6,6,6,7 tiles). 4 waves.
// ---------------------------------------------------------------------------
template <int IN>
__device__ __forceinline__ void dnn_stage_load(const float* __restrict__ x,
                                               int bg, int c, int t,
                                               float4& a, float4& b2) {
  int b = t >> 2, kb = t & 3;
  int k0 = c * 32 + kb * 8;
  if (k0 < IN) {
    const float4* p =
        reinterpret_cast<const float4*>(x + (long)(bg * 64 + b) * IN + k0);
    a = p[0];
    b2 = p[1];
  } else {
    a = make_float4(0.f, 0.f, 0.f, 0.f);
    b2 = make_float4(0.f, 0.f, 0.f, 0.f);
  }
}

__device__ __forceinline__ void dnn_stage_write(__bf16* Xs, int t, float4 a,
                                                float4 b2) {
  int b = t >> 2, kb = t & 3;
  bf16x8 v;
  v[0] = (__bf16)a.x;  v[1] = (__bf16)a.y;  v[2] = (__bf16)a.z;  v[3] = (__bf16)a.w;
  v[4] = (__bf16)b2.x; v[5] = (__bf16)b2.y; v[6] = (__bf16)b2.z; v[7] = (__bf16)b2.w;
  *reinterpret_cast<bf16x8*>(Xs + ((kb * 64 + b) << 3)) = v;
}

template <int W, int TG, int IN, int NCH>
__device__ __forceinline__ void dnn_core(
    const float* __restrict__ x, const __bf16* __restrict__ Wd,
    const float* __restrict__ bias, float* __restrict__ out, __bf16* Xs,
    int bg, int t) {
  constexpr int NT = (TG == 3) ? 7 : 6;
  constexpr int TGB = TG * 6;
  constexpr int PLO = NT * W;
  constexpr int TLO = PLO >> 2;
  constexpr int TN = ((PLO + NT - 1) >> 2) - TLO + 1;
  const int l = t & 63;
  const int q = l >> 4, dd = l & 15;
  const __bf16* wl = Wd + l * 8;

  f32x4 acc[NT] = {};
  bf16x8 wf[TN], wfn[TN];
#pragma unroll
  for (int i = 0; i < TN; ++i)
    wf[i] = *reinterpret_cast<const bf16x8*>(wl + (long)((TGB + TLO + i) * 64) * 8);

  float4 ra, rb;
  dnn_stage_load<IN>(x, bg, 0, t, ra, rb);
  dnn_stage_write(Xs, t, ra, rb);
  lds_barrier();

  for (int c = 0; c < NCH; ++c) {
    __bf16* cur = Xs + (c & 1) * 2048;
    __bf16* nxt = Xs + ((c + 1) & 1) * 2048;
    const bool more = (c + 1 < NCH);
    if (more) {
      dnn_stage_load<IN>(x, bg, c + 1, t, ra, rb);
#pragma unroll
      for (int i = 0; i < TN; ++i)
        wfn[i] = *reinterpret_cast<const bf16x8*>(
            wl + (long)(((c + 1) * 25 + TGB + TLO + i) * 64) * 8);
    }
    bf16x8 bfr[4];
#pragma unroll
    for (int f = 0; f < 4; ++f)
      bfr[f] = *reinterpret_cast<const bf16x8*>(cur + ((q * 64 + f * 16 + dd) << 3));
    __builtin_amdgcn_s_setprio(1);
#pragma unroll
    for (int i = 0; i < NT; ++i) {
      const int p = PLO + i;
      acc[i] = __builtin_amdgcn_mfma_f32_16x16x32_bf16(wf[(p >> 2) - TLO],
                                                       bfr[p & 3], acc[i], 0, 0, 0);
    }
    __builtin_amdgcn_s_setprio(0);
    if (more) dnn_stage_write(nxt, t, ra, rb);
    lds_barrier();
    if (more) {
#pragma unroll
      for (int i = 0; i < TN; ++i) wf[i] = wfn[i];
    }
  }

#pragma unroll
  for (int i = 0; i < NT; ++i) {
    const int p = PLO + i;
    const int gt = TGB + (p >> 2);
    const int f = p & 3;
    const int b = bg * 64 + f * 16 + dd;
#pragma unroll
    for (int r = 0; r < 4; ++r) {
      int o = gt * 16 + q * 4 + r;
      out[(long)b * 400 + o] = fmaxf(acc[i][r] + bias[o], 0.f);
    }
  }
}

template <int IN, int NCH>
__global__ __launch_bounds__(256) void dnn_mfma(
    const float* __restrict__ x, const __bf16* __restrict__ Wd,
    const float* __restrict__ bias, float* __restrict__ out) {
  __shared__ __bf16 Xs[2 * 4 * 64 * 8];
  const int blk = blockIdx.x;
  const int bg = blk >> 2, tg = blk & 3;
  const int t = threadIdx.x;
  const int w = t >> 6;
#define DNN_DISPATCH(TGV)                                                     \
  if (w == 0) dnn_core<0, TGV, IN, NCH>(x, Wd, bias, out, Xs, bg, t);         \
  else if (w == 1) dnn_core<1, TGV, IN, NCH>(x, Wd, bias, out, Xs, bg, t);    \
  else if (w == 2) dnn_core<2, TGV, IN, NCH>(x, Wd, bias, out, Xs, bg, t);    \
  else dnn_core<3, TGV, IN, NCH>(x, Wd, bias, out, Xs, bg, t);
  if (tg == 0) { DNN_DISPATCH(0) }
  else if (tg == 1) { DNN_DISPATCH(1) }
  else if (tg == 2) { DNN_DISPATCH(2) }
  else { DNN_DISPATCH(3) }
#undef DNN_DISPATCH
}

// ---------------------------------------------------------------------------
// K5: final FC + bias-embedding sum
// ---------------------------------------------------------------------------
__global__ __launch_bounds__(256) void final_kernel(
    const float* __restrict__ cin, const float* __restrict__ d1,
    const float* __restrict__ fcW, const float* __restrict__ fcb,
    const float* __restrict__ biassum, float* __restrict__ out) {
  int b = blockIdx.x, t = threadIdx.x;
  float p = 0.f;
  for (int i = t; i < 800; i += 256) {
    float v = (i < 400) ? cin[b * 400 + i] : d1[b * 400 + (i - 400)];
    p += v * fcW[i];
  }
#pragma unroll
  for (int m = 32; m >= 1; m >>= 1) p += __shfl_xor(p, m);
  __shared__ float red[4];
  if ((t & 63) == 0) red[t >> 6] = p;
  __syncthreads();
  if (t == 0) out[b] = red[0] + red[1] + red[2] + red[3] + fcb[0] + biassum[b];
}

// ---------------------------------------------------------------------------
extern "C" void kernel_launch(void* const* d_in, const int* in_sizes, int n_in,
                              void* d_out, int out_size, void* d_ws,
                              size_t ws_size, hipStream_t stream) {
  (void)in_sizes; (void)n_in; (void)out_size; (void)ws_size;
  const int* fid = (const int*)d_in[0];
  const float* fval = (const float*)d_in[1];
  const float* emb = (const float*)d_in[2];
  const float* bias_emb = (const float*)d_in[3];
  const float* cW0 = (const float*)d_in[4];
  const float* cb0 = (const float*)d_in[5];
  const float* cW1 = (const float*)d_in[6];
  const float* cb1 = (const float*)d_in[7];
  const float* cW2 = (const float*)d_in[8];
  const float* cb2 = (const float*)d_in[9];
  const float* dW0 = (const float*)d_in[10];
  const float* db0 = (const float*)d_in[11];
  const float* dW1 = (const float*)d_in[12];
  const float* db1 = (const float*)d_in[13];
  const float* fcW = (const float*)d_in[14];
  const float* fcb = (const float*)d_in[15];
  float* out = (float*)d_out;

  float* ws = (float*)d_ws;
  float* inputs = ws;  ws += B * NF * D;
  float* biassum = ws; ws += B;
  float* cinres = ws;  ws += B * 400;
  float* dd0 = ws;     ws += B * 400;
  float* dd1 = ws;     ws += B * 400;
  __bf16* Wg0 = (__bf16*)ws; ws += (50 * 13 * 64 * 8) / 2;
  __bf16* Wg1 = (__bf16*)ws; ws += (126 * 13 * 64 * 8) / 2;
  __bf16* Wg2 = (__bf16*)ws; ws += (126 * 13 * 64 * 8) / 2;
  __bf16* Wd0 = (__bf16*)ws; ws += (20 * 25 * 64 * 8) / 2;
  __bf16* Wd1 = (__bf16*)ws; ws += (13 * 25 * 64 * 8) / 2;

  gather_kernel<<<B, 256, 0, stream>>>(fid, fval, emb, bias_emb, inputs, biassum);

  prep_all<<<(PREP_TOTAL + 255) / 256, 256, 0, stream>>>(
      cW0, cW1, cW2, dW0, dW1, Wg0, Wg1, Wg2, Wd0, Wd1);

  cin_fused<<<B / 4, 256, 0, stream>>>(inputs, Wg0, Wg1, Wg2, cb0, cb1, cb2, cinres);

  dnn_mfma<624, 20><<<128, 256, 0, stream>>>(inputs, Wd0, db0, dd0);
  dnn_mfma<400, 13><<<128, 256, 0, stream>>>(dd0, Wd1, db1, dd1);

  final_kernel<<<B, 256, 0, stream>>>(cinres, dd1, fcW, fcb, biassum, out);
}